// Round 16
// baseline (1567.719 us; speedup 1.0000x reference)
//
#include <hip/hip_runtime.h>
#include <math.h>

#define CC   1024
#define HH   16
#define DH   64
#define TT   512
#define NTOK 1024     // B*T
#define DFF_ 4096
#define VV   32000
#define QKSCALE 0.125f   // 1/sqrt(64)

typedef unsigned short u16;
typedef __attribute__((ext_vector_type(8))) short short8;
typedef __attribute__((ext_vector_type(4))) float f32x4;

__device__ __forceinline__ u16 f2bf(float f) {   // RNE fp32->bf16
  union { float f; unsigned u; } v; v.f = f;
  unsigned r = v.u + 0x7FFFu + ((v.u >> 16) & 1u);
  return (u16)(r >> 16);
}
__device__ __forceinline__ float gelu_f(float h) {
  return 0.5f * h * (1.0f + tanhf(0.7978845608028654f * (h + 0.044715f * h * h * h)));
}

// counted vmcnt wait (immediate must be literal in asm string)
template <int N> __device__ __forceinline__ void waitcnt_vm() {
  if constexpr (N == 0) asm volatile("s_waitcnt vmcnt(0)" ::: "memory");
  else if constexpr (N == 1) asm volatile("s_waitcnt vmcnt(1)" ::: "memory");
  else if constexpr (N == 2) asm volatile("s_waitcnt vmcnt(2)" ::: "memory");
  else if constexpr (N == 3) asm volatile("s_waitcnt vmcnt(3)" ::: "memory");
  else if constexpr (N == 4) asm volatile("s_waitcnt vmcnt(4)" ::: "memory");
  else if constexpr (N == 5) asm volatile("s_waitcnt vmcnt(5)" ::: "memory");
  else if constexpr (N == 6) asm volatile("s_waitcnt vmcnt(6)" ::: "memory");
  else if constexpr (N == 7) asm volatile("s_waitcnt vmcnt(7)" ::: "memory");
  else if constexpr (N == 8) asm volatile("s_waitcnt vmcnt(8)" ::: "memory");
  else static_assert(N <= 8, "unsupported vmcnt");
}

// async global->LDS, 16B per lane; dest = wave-uniform base + lane*16
#define GLD16(gp, lp) __builtin_amdgcn_global_load_lds( \
    (const __attribute__((address_space(1))) void*)(gp), \
    (__attribute__((address_space(3))) void*)(lp), 16, 0, 0)

#define MFMA(a, b, c) __builtin_amdgcn_mfma_f32_16x16x32_bf16(a, b, c, 0, 0, 0)

// ---------------- embedding ----------------------------------------------
__global__ __launch_bounds__(256) void embed_kernel(
    const int* __restrict__ idx, const float* __restrict__ wte,
    const float* __restrict__ wpe, float* __restrict__ x) {
  int row = blockIdx.x;
  int t = row & (TT - 1);
  int id = idx[row];
  const float4* a = (const float4*)(wte + (size_t)id * CC);
  const float4* p = (const float4*)(wpe + (size_t)t * CC);
  float4* o = (float4*)(x + (size_t)row * CC);
  int c = threadIdx.x;
  float4 va = a[c], vp = p[c];
  float4 ov;
  ov.x = va.x + vp.x; ov.y = va.y + vp.y; ov.z = va.z + vp.z; ov.w = va.w + vp.w;
  o[c] = ov;
}

// ---------------- layernorm (fp32 in -> bf16 out) ------------------------
__global__ __launch_bounds__(256) void ln_kernel(
    const float* __restrict__ x, const float* __restrict__ w,
    const float* __restrict__ b, u16* __restrict__ out) {
  int row = blockIdx.x, tid = threadIdx.x;
  float4 v = ((const float4*)(x + (size_t)row * CC))[tid];
  float s  = v.x + v.y + v.z + v.w;
  float sq = fmaf(v.x, v.x, fmaf(v.y, v.y, fmaf(v.z, v.z, v.w * v.w)));
  for (int o = 32; o > 0; o >>= 1) { s += __shfl_down(s, o); sq += __shfl_down(sq, o); }
  __shared__ float rs[4], rq[4];
  int wid = tid >> 6, lane = tid & 63;
  if (lane == 0) { rs[wid] = s; rq[wid] = sq; }
  __syncthreads();
  s  = rs[0] + rs[1] + rs[2] + rs[3];
  sq = rq[0] + rq[1] + rq[2] + rq[3];
  float mean = s * (1.0f / CC);
  float var  = sq * (1.0f / CC) - mean * mean;
  float rstd = 1.0f / sqrtf(var + 1e-5f);
  float4 wv = ((const float4*)w)[tid];
  float4 bv = ((const float4*)b)[tid];
  ushort4 o;
  o.x = f2bf((v.x - mean) * rstd * wv.x + bv.x);
  o.y = f2bf((v.y - mean) * rstd * wv.y + bv.y);
  o.z = f2bf((v.z - mean) * rstd * wv.z + bv.z);
  o.w = f2bf((v.w - mean) * rstd * wv.w + bv.w);
  ((ushort4*)(out + (size_t)row * CC))[tid] = o;
}

// ---------------- weight prep: 16 transposes per layer, z = l*16 + slot --
// slot 0-7: square weights; 8-11: fc col-slices; 12-15: pr row-slices.
// 64x64 tiles: 256B-coalesced reads, 128B-coalesced u16 writes.
__global__ __launch_bounds__(256) void wtransL_kernel(
    const float* __restrict__ w0, const float* __restrict__ w1,
    const float* __restrict__ w2, const float* __restrict__ w3,
    const float* __restrict__ w4, const float* __restrict__ w5,
    const float* __restrict__ w6, const float* __restrict__ w7,
    const float* __restrict__ fc, const float* __restrict__ pr,
    u16* __restrict__ wt, size_t dls, int lbase) {
  const size_t M1 = 1048576;
  int z = blockIdx.z;
  int l = lbase + (z >> 4), slot = z & 15;
  size_t wofs = (size_t)l * M1;          // square weights: l*C*C
  size_t mofs = (size_t)l * 4 * M1;      // fc/pr: l*C*DFF
  const float* src;
  size_t doff = (size_t)(l - lbase) * dls;
  int sstr, dstr;
  if (slot < 8) {
    const float* base = slot == 0 ? w0 : slot == 1 ? w1 : slot == 2 ? w2
                      : slot == 3 ? w3 : slot == 4 ? w4 : slot == 5 ? w5
                      : slot == 6 ? w6 : w7;
    src = base + wofs; sstr = 1024; doff += (size_t)slot * M1; dstr = 1024;
  } else if (slot < 12) {
    int s = slot - 8;
    src = fc + mofs + (size_t)s * 1024; sstr = 4096;
    doff += 8 * M1 + (size_t)s * M1; dstr = 1024;
  } else {
    int s = slot - 12;
    src = pr + mofs + (size_t)s * M1; sstr = 1024;
    doff += 12 * M1 + (size_t)s * 1024; dstr = 4096;
  }
  __shared__ float t[64][65];
  int bx = blockIdx.x * 64, by = blockIdx.y * 64;
  int tid = threadIdx.x;
  int r16 = tid >> 4;          // 0..15
  int c4  = (tid & 15) * 4;    // 0..60
#pragma unroll
  for (int i = 0; i < 4; ++i) {
    int row = r16 + i * 16;
    float4 v = *(const float4*)&src[(size_t)(by + row) * sstr + bx + c4];
    t[row][c4] = v.x; t[row][c4 + 1] = v.y; t[row][c4 + 2] = v.z; t[row][c4 + 3] = v.w;
  }
  __syncthreads();
#pragma unroll
  for (int i = 0; i < 4; ++i) {
    int orow = r16 + i * 16;   // output row n = bx+orow; k = by+c4..+3
    ushort4 o;
    o.x = f2bf(t[c4 + 0][orow]);
    o.y = f2bf(t[c4 + 1][orow]);
    o.z = f2bf(t[c4 + 2][orow]);
    o.w = f2bf(t[c4 + 3][orow]);
    *(ushort4*)&wt[doff + (size_t)(bx + orow) * dstr + by + c4] = o;
  }
}

// ---------------- elementwise f32 -> bf16 --------------------------------
__global__ __launch_bounds__(256) void convbf_kernel(
    const float* __restrict__ in, u16* __restrict__ out, int n4) {
  int i = blockIdx.x * 256 + threadIdx.x;
  if (i < n4) {
    float4 v = ((const float4*)in)[i];
    ushort4 o; o.x = f2bf(v.x); o.y = f2bf(v.y); o.z = f2bf(v.z); o.w = f2bf(v.w);
    ((ushort4*)out)[i] = o;
  }
}

// ---------------- bf16 MFMA GEMM, XOR-swizzled LDS -----------------------
// C[M,N](ldc) = epi(A[M,K] @ B^T + bias);  A[M,K], B[N,K] bf16 row-major.
// Tile BM x BN, 4 waves of (BM/2)x(BN/2); K-step BK (64 or 32).
// MODE 0/3: triple-buffered counted-vmcnt pipeline (2 stages in flight).
// MODE 2: lm_head (XCD swizzle + B reg-staged from f32, BK=64, T14 split:
//   loads issued one K-step ahead; per-iter latency exposure ~halved vs BK=32).
// EPI: 0=store f32(+bias), 1=f32 += residual (atomic when SK>1),
//      2=bf16 gelu(+bias), 4=bf16 per-head scatter
// SK: split-K factor (blockIdx.z selects split; bias applied by split 0)
template <int EPI, int MODE, int BM, int BN, int BK, int SK>
__global__ __launch_bounds__(256) void gemm_bf16_kernel(
    const u16* __restrict__ A, const u16* __restrict__ A2,
    const u16* __restrict__ B, const u16* __restrict__ B2,
    const float* __restrict__ bias, const float* __restrict__ bias2,
    const float* __restrict__ bias3, float* __restrict__ Cm,
    int K, int ldc, int whichbase) {
  constexpr int WM = BM / 2, WN = BN / 2, MF = WM / 16, NF = WN / 16;
  constexpr int KS = BK / 32;
  constexpr int NB = BK / 8;
  constexpr int PA = BM * BK / 2048;
  constexpr int PB = BN * BK / 2048;
  constexpr int RPP = 2048 / BK;
  constexpr int NBUF = (MODE == 2) ? 2 : 3;
  __shared__ u16 As[NBUF][BM * BK];
  __shared__ u16 Bs[NBUF][BN * BK];
  int tid = threadIdx.x;
  int lane = tid & 63, wave = tid >> 6;
  int wr = wave >> 1, wc = wave & 1;
  int row0, col0;
  bool isq = true;
  const u16* Ause = A;
  const u16* Buse = B;
  if (MODE == 2) {
    int id = blockIdx.x;                 // 0..1999
    int wg = (id & 7) * 250 + (id >> 3); // bijective XCD swizzle
    row0 = (wg & 7) * BM;
    col0 = (wg >> 3) * BN;
  } else if (MODE == 3) {
    int bx = blockIdx.x;
    isq = bx < (1024 / BN);
    Ause = isq ? A : A2;
    Buse = isq ? B : B2;
    col0 = (isq ? bx : bx - 1024 / BN) * BN;
    row0 = blockIdx.y * BM;
  } else {
    row0 = blockIdx.y * BM;
    col0 = blockIdx.x * BN;
  }
  const int split = (SK > 1) ? blockIdx.z : 0;
  const int Kloc = K / SK;
  const int kbase = split * Kloc;
  f32x4 acc[MF][NF];
#pragma unroll
  for (int m = 0; m < MF; ++m)
#pragma unroll
    for (int n = 0; n < NF; ++n) acc[m][n] = (f32x4){0.f, 0.f, 0.f, 0.f};

  int srow = tid / NB;
  int sblk = (BK == 64) ? ((tid & 7) ^ ((tid >> 3) & 7))
                        : ((tid & 3) ^ ((tid >> 3) & 3));
  const u16* Ab = Ause + (size_t)row0 * K + kbase;
  int arow = wr * WM + (lane & 15);
  int brow = wc * WN + (lane & 15);
  int g8 = lane >> 4;
  const int NT = Kloc / BK;

  auto compute = [&](const u16* Ac, const u16* Bc) {
#pragma unroll
    for (int ks = 0; ks < KS; ++ks) {
      short8 af[MF], bg[NF];
#pragma unroll
      for (int m = 0; m < MF; ++m) {
        int row = arow + m * 16;
        int off = (BK == 64) ? row * 64 + (((ks * 4 + g8) ^ (row & 7)) << 3)
                             : row * 32 + ((g8 ^ ((row >> 1) & 3)) << 3);
        af[m] = *(const short8*)&Ac[off];
      }
#pragma unroll
      for (int n = 0; n < NF; ++n) {
        int row = brow + n * 16;
        int off = (BK == 64) ? row * 64 + (((ks * 4 + g8) ^ (row & 7)) << 3)
                             : row * 32 + ((g8 ^ ((row >> 1) & 3)) << 3);
        bg[n] = *(const short8*)&Bc[off];
      }
      __builtin_amdgcn_s_setprio(1);
#pragma unroll
      for (int m = 0; m < MF; ++m)
#pragma unroll
        for (int n = 0; n < NF; ++n)
          acc[m][n] = MFMA(af[m], bg[n], acc[m][n]);
      __builtin_amdgcn_s_setprio(0);
    }
  };

  if constexpr (MODE == 2) {
    // B reg-staged from f32 (wte is [N][K] f32), BK=64.
    // Thread t: B-row = t>>1 (0..127), k-half = (t&1)*32; 8x float4 = 32 f32.
    const float* Bf = (const float*)B;
    int browS = tid >> 1;
    int khalf = (tid & 1) * 32;
    float4 rb[8];
    auto loadB = [&](int k0) {
      const float* p = Bf + (size_t)(col0 + browS) * 1024 + k0 + khalf;
#pragma unroll
      for (int j = 0; j < 8; ++j) rb[j] = *(const float4*)(p + j * 4);
    };
    auto writeB = [&](int bufi) {
#pragma unroll
      for (int j = 0; j < 4; ++j) {   // 4 x short8 (8 bf16 each)
        u16 tmp[8] = {f2bf(rb[2*j].x), f2bf(rb[2*j].y), f2bf(rb[2*j].z), f2bf(rb[2*j].w),
                      f2bf(rb[2*j+1].x), f2bf(rb[2*j+1].y), f2bf(rb[2*j+1].z), f2bf(rb[2*j+1].w)};
        int blk = (khalf >> 3) + j;   // 16B-block index 0..7
        *(short8*)&Bs[bufi][browS * 64 + ((blk ^ (browS & 7)) << 3)] = *(short8*)tmp;
      }
    };
    auto stageA = [&](int bufi, int k0) {
#pragma unroll
      for (int p = 0; p < PA; ++p)
        GLD16(Ab + (size_t)(p * RPP + srow) * K + k0 + sblk * 8,
              &As[bufi][p * 2048 + wave * 512]);
    };
    loadB(0);
    stageA(0, 0);
    writeB(0);
    __syncthreads();
    for (int t = 0; t < NT; ++t) {
      int cur = t & 1;
      if (t + 1 < NT) { loadB((t + 1) * BK); stageA(cur ^ 1, (t + 1) * BK); }
      compute(As[cur], Bs[cur]);
      if (t + 1 < NT) writeB(cur ^ 1);   // cvt+ds_write after MFMAs (T14)
      __syncthreads();
    }
  } else {
    const u16* Bb = Buse + (size_t)col0 * K + kbase;
    auto stage = [&](int bufi, int k0) {
#pragma unroll
      for (int p = 0; p < PA; ++p)
        GLD16(Ab + (size_t)(p * RPP + srow) * K + k0 + sblk * 8,
              &As[bufi][p * 2048 + wave * 512]);
#pragma unroll
      for (int p = 0; p < PB; ++p)
        GLD16(Bb + (size_t)(p * RPP + srow) * K + k0 + sblk * 8,
              &Bs[bufi][p * 2048 + wave * 512]);
    };
    // T4 pipeline: 2 stages in flight, counted vmcnt, raw barriers.
    stage(0, 0);
    if (NT > 1) stage(1, BK);
    for (int t = 0; t < NT; ++t) {
      if (t + 1 < NT) waitcnt_vm<PA + PB>();  // tile t resident; t+1 in flight
      else            waitcnt_vm<0>();        // final drain
      __builtin_amdgcn_s_barrier();
      __builtin_amdgcn_sched_barrier(0);
      if (t + 2 < NT) stage((t + 2) % 3, (t + 2) * BK);
      int cur = t % 3;
      compute(As[cur], Bs[cur]);
      // no trailing barrier: 3 buffers + next-iter barrier protect reuse
    }
  }

  int r0 = row0 + wr * WM + g8 * 4;
  int c0 = col0 + wc * WN + (lane & 15);

  if (EPI == 4) {
    // scatter to per-head layouts: q/k [bh][t][d], v [bh][d][t]
    u16* qb = (u16*)Cm;
#pragma unroll
    for (int m = 0; m < MF; ++m)
#pragma unroll
      for (int n = 0; n < NF; ++n) {
        int j = c0 + n * 16;
        int which = (MODE == 3 ? (isq ? 0 : 1) : whichbase) + (j >> 10);
        const float* bp = which == 0 ? bias : (which == 1 ? bias2 : bias3);
        float bj = bp ? bp[j & 1023] : 0.0f;
        int h = (j & 1023) >> 6, d = j & 63;
        int trow0 = r0 + m * 16;
        int b = trow0 >> 9, t0 = trow0 & 511;
        int bh = b * 16 + h;
        u16 vals[4];
#pragma unroll
        for (int r = 0; r < 4; ++r) vals[r] = f2bf(acc[m][n][r] + bj);
        if (which < 2) {
          u16* dst = qb + (size_t)which * 1048576 + (size_t)bh * 32768 + (size_t)t0 * 64 + d;
#pragma unroll
          for (int r = 0; r < 4; ++r) dst[(size_t)r * 64] = vals[r];
        } else {
          u16* dst = qb + 2 * 1048576 + (size_t)bh * 32768 + (size_t)d * 512 + t0;
          *(ushort4*)dst = *(ushort4*)vals;
        }
      }
    return;
  }

  float bj[NF];
#pragma unroll
  for (int n = 0; n < NF; ++n)
    bj[n] = bias ? bias[c0 + n * 16] : 0.0f;
  u16* Cb = (u16*)Cm;
#pragma unroll
  for (int m = 0; m < MF; ++m)
#pragma unroll
    for (int n = 0; n < NF; ++n)
#pragma unroll
      for (int r = 0; r < 4; ++r) {
        size_t off = (size_t)(r0 + m * 16 + r) * ldc + c0 + n * 16;
        float v = acc[m][n][r] + ((SK == 1 || split == 0) ? bj[n] : 0.0f);
        if (EPI == 0) Cm[off] = v;
        else if (EPI == 1) {
          if constexpr (SK > 1) atomicAdd(&Cm[off], v);
          else Cm[off] += v;
        }
        else if (EPI == 2) Cb[off] = f2bf(gelu_f(v));
      }
}

// ---------------- fused flash attention (causal, incl. cross per ref) ----
// q,k: [32 bh][512 t][64 d] bf16;  v: [32 bh][64 d][512 t] bf16
// y: [1024 tok][1024 C] bf16.  Grid (16 q-tiles, 32 bh), 256 threads.
__global__ __launch_bounds__(256) void attn_kernel(
    const u16* __restrict__ qh, const u16* __restrict__ kh,
    const u16* __restrict__ vt, u16* __restrict__ y) {
  __shared__ u16 P[32 * 512];             // swizzled probs
  __shared__ float smax[4][32], ssum[4][32];
  int tid = threadIdx.x, lane = tid & 63, w = tid >> 6;
  int bx = blockIdx.x, bh = blockIdx.y;
  int q0 = bx * 32;
  int b = bh >> 4, h = bh & 15;
  const u16* qb = qh + (size_t)bh * 32768;
  const u16* kb = kh + (size_t)bh * 32768;
  const u16* vb = vt + (size_t)bh * 32768;
  int g = lane >> 4, c = lane & 15;

  short8 a[2][2];
#pragma unroll
  for (int rt = 0; rt < 2; ++rt)
#pragma unroll
    for (int ks = 0; ks < 2; ++ks)
      a[rt][ks] = *(const short8*)(qb + (size_t)(q0 + rt * 16 + c) * 64 + ks * 32 + g * 8);

  int lim = q0 + 31;
  int nct = (lim - w * 128) / 16 + 1;
  if (nct > 8) nct = 8;
  if (nct < 0) nct = 0;
  f32x4 s[2][8];
#pragma unroll
  for (int rt = 0; rt < 2; ++rt)
#pragma unroll
    for (int ct = 0; ct < 8; ++ct) s[rt][ct] = (f32x4){0.f, 0.f, 0.f, 0.f};
  for (int ct = 0; ct < nct; ++ct) {
    int n0 = w * 128 + ct * 16;
#pragma unroll
    for (int ks = 0; ks < 2; ++ks) {
      short8 bf = *(const short8*)(kb + (size_t)(n0 + c) * 64 + ks * 32 + g * 8);
      s[0][ct] = MFMA(a[0][ks], bf, s[0][ct]);
      s[1][ct] = MFMA(a[1][ks], bf, s[1][ct]);
    }
  }

  float mx[2][4];
#pragma unroll
  for (int rt = 0; rt < 2; ++rt)
#pragma unroll
    for (int r = 0; r < 4; ++r) mx[rt][r] = -1e30f;
  for (int ct = 0; ct < nct; ++ct) {
    int col = w * 128 + ct * 16 + c;
#pragma unroll
    for (int rt = 0; rt < 2; ++rt)
#pragma unroll
      for (int r = 0; r < 4; ++r) {
        int trow = q0 + rt * 16 + g * 4 + r;
        float v = s[rt][ct][r] * QKSCALE;
        if (col > trow) v = -1e30f;
        s[rt][ct][r] = v;
        mx[rt][r] = fmaxf(mx[rt][r], v);
      }
  }
#pragma unroll
  for (int off = 1; off < 16; off <<= 1)
#pragma unroll
    for (int rt = 0; rt < 2; ++rt)
#pragma unroll
      for (int r = 0; r < 4; ++r) mx[rt][r] = fmaxf(mx[rt][r], __shfl_xor(mx[rt][r], off));
  if (c == 0)
#pragma unroll
    for (int rt = 0; rt < 2; ++rt)
#pragma unroll
      for (int r = 0; r < 4; ++r) smax[w][rt * 16 + g * 4 + r] = mx[rt][r];
  __syncthreads();

  float m_[2][4], sum[2][4];
#pragma unroll
  for (int rt = 0; rt < 2; ++rt)
#pragma unroll
    for (int r = 0; r < 4; ++r) {
      int row = rt * 16 + g * 4 + r;
      m_[rt][r] = fmaxf(fmaxf(smax[0][row], smax[1][row]), fmaxf(smax[2][row], smax[3][row]));
      sum[rt][r] = 0.f;
    }
  for (int ct = 0; ct < nct; ++ct) {
    int col = w * 128 + ct * 16 + c;
    int blk = col >> 3, cl = col & 7;
#pragma unroll
    for (int rt = 0; rt < 2; ++rt)
#pragma unroll
      for (int r = 0; r < 4; ++r) {
        float p = __expf(s[rt][ct][r] - m_[rt][r]);
        sum[rt][r] += p;
        int row = rt * 16 + g * 4 + r;
        int hsh = (row ^ (row >> 2)) & 7;
        P[row * 512 + ((blk ^ hsh) << 3) + cl] = f2bf(p);
      }
  }
#pragma unroll
  for (int off = 1; off < 16; off <<= 1)
#pragma unroll
    for (int rt = 0; rt < 2; ++rt)
#pragma unroll
      for (int r = 0; r < 4; ++r) sum[rt][r] += __shfl_xor(sum[rt][r], off);
  if (c == 0)
#pragma unroll
    for (int rt = 0; rt < 2; ++rt)
#pragma unroll
      for (int r = 0; r < 4; ++r) ssum[w][rt * 16 + g * 4 + r] = sum[rt][r];
  __syncthreads();

  float li[2][4];
#pragma unroll
  for (int rt = 0; rt < 2; ++rt)
#pragma unroll
    for (int r = 0; r < 4; ++r) {
      int row = rt * 16 + g * 4 + r;
      li[rt][r] = 1.0f / (ssum[0][row] + ssum[1][row] + ssum[2][row] + ssum[3][row]);
    }

  int rt2 = w >> 1, nh = w & 1;
  f32x4 o[2];
  o[0] = (f32x4){0.f, 0.f, 0.f, 0.f};
  o[1] = (f32x4){0.f, 0.f, 0.f, 0.f};
  int nks = bx + 1;
  int prow = rt2 * 16 + c;
  int phsh = (prow ^ (prow >> 2)) & 7;
  for (int ks = 0; ks < nks; ++ks) {
    short8 pa = *(const short8*)&P[prow * 512 + (((ks * 4 + g) ^ phsh) << 3)];
#pragma unroll
    for (int nt = 0; nt < 2; ++nt) {
      int d = nh * 32 + nt * 16 + c;
      short8 vf = *(const short8*)(vb + (size_t)d * 512 + ks * 32 + g * 8);
      o[nt] = MFMA(pa, vf, o[nt]);
    }
  }
#pragma unroll
  for (int nt = 0; nt < 2; ++nt)
#pragma unroll
    for (int r = 0; r < 4; ++r) {
      int trow = q0 + rt2 * 16 + g * 4 + r;
      float val = o[nt][r] * li[rt2][r];
      y[(size_t)(b * 512 + trow) * 1024 + h * 64 + nh * 32 + nt * 16 + c] = f2bf(val);
    }
}

// ---------------- launch ---------------------------------------------------
extern "C" void kernel_launch(void* const* d_in, const int* in_sizes, int n_in,
                              void* d_out, int out_size, void* d_ws, size_t ws_size,
                              hipStream_t stream) {
  const int*   idx   = (const int*)d_in[0];
  const float* xa    = (const float*)d_in[1];
  const float* wte   = (const float*)d_in[2];
  const float* wpe   = (const float*)d_in[3];
  const float* ln1_w = (const float*)d_in[4];
  const float* ln1_b = (const float*)d_in[5];
  const float* sa_wq = (const float*)d_in[6];
  const float* sa_bq = (const float*)d_in[7];
  const float* sa_wk = (const float*)d_in[8];
  const float* sa_bk = (const float*)d_in[9];
  const float* sa_wv = (const float*)d_in[10];
  const float* sa_bv = (const float*)d_in[11];
  const float* sa_wo = (const float*)d_in[12];
  const float* sa_bo = (const float*)d_in[13];
  const float* ca_wq = (const float*)d_in[14];
  const float* ca_bq = (const float*)d_in[15];
  const float* ca_wk = (const float*)d_in[16];
  const float* ca_bk = (const float*)d_in[17];
  const float* ca_wv = (const float*)d_in[18];
  const float* ca_bv = (const float*)d_in[19];
  const float* ca_wo = (const float*)d_in[20];
  const float* ca_bo = (const float*)d_in[21];
  const float* ln2_w = (const float*)d_in[22];
  const float* ln2_b = (const float*)d_in[23];
  const float* fc_w  = (const float*)d_in[24];
  const float* fc_b  = (const float*)d_in[25];
  const float* pr_w  = (const float*)d_in[26];
  const float* pr_b  = (const float*)d_in[27];
  const float* lnf_w = (const float*)d_in[28];
  const float* lnf_b = (const float*)d_in[29];

  const size_t M1 = 1048576;
  float* ws     = (float*)d_ws;
  float* x      = ws;                    // [1024,1024] f32  (4 MB)
  u16* qkvh  = (u16*)(x + M1);           // q,k: [32][512][64]; v: [32][64][512]
  u16* nbf   = qkvh + 3 * M1;            // [1024,1024] bf16
  u16* ybf   = nbf + M1;                 // [1024,1024] bf16
  u16* hmbf  = ybf + M1;                 // [1024,4096] bf16
  u16* xabf  = hmbf + 4 * M1;            // [1024,1024] bf16
  u16* wT    = xabf + M1;                // per-layer (32MB) or 6-layer (192MB)

  // full-prep mode needs 4MB + 20MB + 192MB = 226,492,416 B of workspace
  const bool full = ws_size >= 226492416ull;
  const size_t wls = full ? 16 * M1 : 0;   // wT layer stride (elems)

  const size_t oQKV = 0, oWO = 3 * M1, oCQ = 4 * M1, oCKV = 5 * M1,
               oCWO = 7 * M1, oFC = 8 * M1, oPR = 12 * M1;

  embed_kernel<<<NTOK, 256, 0, stream>>>(idx, wte, wpe, x);
  convbf_kernel<<<(NTOK * CC / 4 + 255) / 256, 256, 0, stream>>>(xa, xabf, NTOK * CC / 4);
  if (full)   // all 6 layers' weight prep in ONE saturated dispatch
    wtransL_kernel<<<dim3(16, 16, 96), 256, 0, stream>>>(
        sa_wq, sa_wk, sa_wv, sa_wo, ca_wq, ca_wk, ca_wv, ca_wo,
        fc_w, pr_w, wT, wls, 0);

  for (int l = 0; l < 6; ++l) {
    size_t bofs = (size_t)l * CC;
    u16* wTl = wT + (size_t)l * wls;

    if (!full)
      wtransL_kernel<<<dim3(16, 16, 16), 256, 0, stream>>>(
          sa_wq, sa_wk, sa_wv, sa_wo, ca_wq, ca_wk, ca_wv, ca_wo,
          fc_w, pr_w, wT, 0, l);

    // ---- self attention ----
    ln_kernel<<<NTOK, 256, 0, stream>>>(x, ln1_w + bofs, ln1_b + bofs, nbf);
    gemm_bf16_kernel<4, 0, 64, 128, 64, 1><<<dim3(24, 16), 256, 0, stream>>>(
        nbf, nullptr, wTl + oQKV, nullptr, sa_bq + bofs, sa_bk + bofs,
        sa_bv + bofs, (float*)qkvh, CC, 0, 0);
    attn_kernel<<<dim3(16, 32), 256, 0, stream>>>(qkvh, qkvh + M1, qkvh + 2 * M1, ybf);
    gemm_bf16_kernel<1, 0, 32, 64, 64, 2><<<dim3(16, 32, 2), 256, 0, stream>>>(
        ybf, nullptr, wTl + oWO, nullptr, sa_bo + bofs, nullptr, nullptr,
        x, CC, CC, 0);

    // ---- cross attention: cq | ckv merged (independent inputs) ----
    ln_kernel<<<NTOK, 256, 0, stream>>>(x, ln1_w + bofs, ln1_b + bofs, nbf);
    gemm_bf16_kernel<4, 3, 64, 64, 64, 1><<<dim3(48, 16), 256, 0, stream>>>(
        nbf, xabf, wTl + oCQ, wTl + oCKV, ca_bq + bofs, ca_bk + bofs,
        ca_bv + bofs, (float*)qkvh, CC, 0, 0);
    attn_kernel<<<dim3(16, 32), 256, 0, stream>>>(qkvh, qkvh + M1, qkvh + 2 * M1, ybf);
    gemm_bf16_kernel<1, 0, 32, 64, 64, 2><<<dim3(16, 32, 2), 256, 0, stream>>>(
        ybf, nullptr, wTl + oCWO, nullptr, ca_bo + bofs, nullptr, nullptr,
        x, CC, CC, 0);

    // ---- MLP ----
    ln_kernel<<<NTOK, 256, 0, stream>>>(x, ln2_w + bofs, ln2_b + bofs, nbf);
    gemm_bf16_kernel<2, 0, 64, 128, 64, 1><<<dim3(32, 16), 256, 0, stream>>>(
        nbf, nullptr, wTl + oFC, nullptr, fc_b + (size_t)l * DFF_, nullptr,
        nullptr, (float*)hmbf, CC, DFF_, 0);
    gemm_bf16_kernel<1, 0, 32, 64, 64, 4><<<dim3(16, 32, 4), 256, 0, stream>>>(
        hmbf, nullptr, wTl + oPR, nullptr, pr_b + bofs, nullptr, nullptr,
        x, DFF_, CC, 0);
  }

  // ---- final LN + tied lm_head: B staged from wte f32, BK=64 ----
  ln_kernel<<<NTOK, 256, 0, stream>>>(x, lnf_w, lnf_b, nbf);
  gemm_bf16_kernel<0, 2, 128, 128, 64, 1><<<dim3(2000), 256, 0, stream>>>(
      nbf, nullptr, (const u16*)wte, nullptr, nullptr, nullptr, nullptr,
      (float*)d_out, CC, VV, 0);
}

// Round 17
// 1509.478 us; speedup vs baseline: 1.0386x; 1.0386x over previous
//
#include <hip/hip_runtime.h>
#include <math.h>

#define CC   1024
#define HH   16
#define DH   64
#define TT   512
#define NTOK 1024     // B*T
#define DFF_ 4096
#define VV   32000
#define QKSCALE 0.125f   // 1/sqrt(64)

typedef unsigned short u16;
typedef __attribute__((ext_vector_type(8))) short short8;
typedef __attribute__((ext_vector_type(4))) float f32x4;

__device__ __forceinline__ u16 f2bf(float f) {   // RNE fp32->bf16
  union { float f; unsigned u; } v; v.f = f;
  unsigned r = v.u + 0x7FFFu + ((v.u >> 16) & 1u);
  return (u16)(r >> 16);
}
__device__ __forceinline__ float gelu_f(float h) {
  return 0.5f * h * (1.0f + tanhf(0.7978845608028654f * (h + 0.044715f * h * h * h)));
}

// counted vmcnt wait (immediate must be literal in asm string)
template <int N> __device__ __forceinline__ void waitcnt_vm() {
  if constexpr (N == 0) asm volatile("s_waitcnt vmcnt(0)" ::: "memory");
  else if constexpr (N == 1) asm volatile("s_waitcnt vmcnt(1)" ::: "memory");
  else if constexpr (N == 2) asm volatile("s_waitcnt vmcnt(2)" ::: "memory");
  else if constexpr (N == 3) asm volatile("s_waitcnt vmcnt(3)" ::: "memory");
  else if constexpr (N == 4) asm volatile("s_waitcnt vmcnt(4)" ::: "memory");
  else if constexpr (N == 5) asm volatile("s_waitcnt vmcnt(5)" ::: "memory");
  else if constexpr (N == 6) asm volatile("s_waitcnt vmcnt(6)" ::: "memory");
  else if constexpr (N == 7) asm volatile("s_waitcnt vmcnt(7)" ::: "memory");
  else if constexpr (N == 8) asm volatile("s_waitcnt vmcnt(8)" ::: "memory");
  else static_assert(N <= 8, "unsupported vmcnt");
}

// async global->LDS, 16B per lane; dest = wave-uniform base + lane*16
#define GLD16(gp, lp) __builtin_amdgcn_global_load_lds( \
    (const __attribute__((address_space(1))) void*)(gp), \
    (__attribute__((address_space(3))) void*)(lp), 16, 0, 0)

#define MFMA(a, b, c) __builtin_amdgcn_mfma_f32_16x16x32_bf16(a, b, c, 0, 0, 0)

// ---------------- embedding ----------------------------------------------
__global__ __launch_bounds__(256) void embed_kernel(
    const int* __restrict__ idx, const float* __restrict__ wte,
    const float* __restrict__ wpe, float* __restrict__ x) {
  int row = blockIdx.x;
  int t = row & (TT - 1);
  int id = idx[row];
  const float4* a = (const float4*)(wte + (size_t)id * CC);
  const float4* p = (const float4*)(wpe + (size_t)t * CC);
  float4* o = (float4*)(x + (size_t)row * CC);
  int c = threadIdx.x;
  float4 va = a[c], vp = p[c];
  float4 ov;
  ov.x = va.x + vp.x; ov.y = va.y + vp.y; ov.z = va.z + vp.z; ov.w = va.w + vp.w;
  o[c] = ov;
}

// ---------------- layernorm (fp32 in -> bf16 out) ------------------------
__global__ __launch_bounds__(256) void ln_kernel(
    const float* __restrict__ x, const float* __restrict__ w,
    const float* __restrict__ b, u16* __restrict__ out) {
  int row = blockIdx.x, tid = threadIdx.x;
  float4 v = ((const float4*)(x + (size_t)row * CC))[tid];
  float s  = v.x + v.y + v.z + v.w;
  float sq = fmaf(v.x, v.x, fmaf(v.y, v.y, fmaf(v.z, v.z, v.w * v.w)));
  for (int o = 32; o > 0; o >>= 1) { s += __shfl_down(s, o); sq += __shfl_down(sq, o); }
  __shared__ float rs[4], rq[4];
  int wid = tid >> 6, lane = tid & 63;
  if (lane == 0) { rs[wid] = s; rq[wid] = sq; }
  __syncthreads();
  s  = rs[0] + rs[1] + rs[2] + rs[3];
  sq = rq[0] + rq[1] + rq[2] + rq[3];
  float mean = s * (1.0f / CC);
  float var  = sq * (1.0f / CC) - mean * mean;
  float rstd = 1.0f / sqrtf(var + 1e-5f);
  float4 wv = ((const float4*)w)[tid];
  float4 bv = ((const float4*)b)[tid];
  ushort4 o;
  o.x = f2bf((v.x - mean) * rstd * wv.x + bv.x);
  o.y = f2bf((v.y - mean) * rstd * wv.y + bv.y);
  o.z = f2bf((v.z - mean) * rstd * wv.z + bv.z);
  o.w = f2bf((v.w - mean) * rstd * wv.w + bv.w);
  ((ushort4*)(out + (size_t)row * CC))[tid] = o;
}

// ---------------- weight prep: 16 transposes per layer, z = l*16 + slot --
__global__ __launch_bounds__(256) void wtransL_kernel(
    const float* __restrict__ w0, const float* __restrict__ w1,
    const float* __restrict__ w2, const float* __restrict__ w3,
    const float* __restrict__ w4, const float* __restrict__ w5,
    const float* __restrict__ w6, const float* __restrict__ w7,
    const float* __restrict__ fc, const float* __restrict__ pr,
    u16* __restrict__ wt, size_t dls, int lbase) {
  const size_t M1 = 1048576;
  int z = blockIdx.z;
  int l = lbase + (z >> 4), slot = z & 15;
  size_t wofs = (size_t)l * M1;          // square weights: l*C*C
  size_t mofs = (size_t)l * 4 * M1;      // fc/pr: l*C*DFF
  const float* src;
  size_t doff = (size_t)(l - lbase) * dls;
  int sstr, dstr;
  if (slot < 8) {
    const float* base = slot == 0 ? w0 : slot == 1 ? w1 : slot == 2 ? w2
                      : slot == 3 ? w3 : slot == 4 ? w4 : slot == 5 ? w5
                      : slot == 6 ? w6 : w7;
    src = base + wofs; sstr = 1024; doff += (size_t)slot * M1; dstr = 1024;
  } else if (slot < 12) {
    int s = slot - 8;
    src = fc + mofs + (size_t)s * 1024; sstr = 4096;
    doff += 8 * M1 + (size_t)s * M1; dstr = 1024;
  } else {
    int s = slot - 12;
    src = pr + mofs + (size_t)s * M1; sstr = 1024;
    doff += 12 * M1 + (size_t)s * 1024; dstr = 4096;
  }
  __shared__ float t[64][65];
  int bx = blockIdx.x * 64, by = blockIdx.y * 64;
  int tid = threadIdx.x;
  int r16 = tid >> 4;          // 0..15
  int c4  = (tid & 15) * 4;    // 0..60
#pragma unroll
  for (int i = 0; i < 4; ++i) {
    int row = r16 + i * 16;
    float4 v = *(const float4*)&src[(size_t)(by + row) * sstr + bx + c4];
    t[row][c4] = v.x; t[row][c4 + 1] = v.y; t[row][c4 + 2] = v.z; t[row][c4 + 3] = v.w;
  }
  __syncthreads();
#pragma unroll
  for (int i = 0; i < 4; ++i) {
    int orow = r16 + i * 16;   // output row n = bx+orow; k = by+c4..+3
    ushort4 o;
    o.x = f2bf(t[c4 + 0][orow]);
    o.y = f2bf(t[c4 + 1][orow]);
    o.z = f2bf(t[c4 + 2][orow]);
    o.w = f2bf(t[c4 + 3][orow]);
    *(ushort4*)&wt[doff + (size_t)(bx + orow) * dstr + by + c4] = o;
  }
}

// ---------------- elementwise f32 -> bf16 --------------------------------
__global__ __launch_bounds__(256) void convbf_kernel(
    const float* __restrict__ in, u16* __restrict__ out, int n4) {
  int i = blockIdx.x * 256 + threadIdx.x;
  if (i < n4) {
    float4 v = ((const float4*)in)[i];
    ushort4 o; o.x = f2bf(v.x); o.y = f2bf(v.y); o.z = f2bf(v.z); o.w = f2bf(v.w);
    ((ushort4*)out)[i] = o;
  }
}

// ---------------- bf16 MFMA GEMM, XOR-swizzled LDS -----------------------
// C[M,N](ldc) = epi(A[M,K] @ B^T + bias);  A[M,K], B[N,K] bf16 row-major.
// Tile BM x BN, 4 waves of (BM/2)x(BN/2); K-step BK (64 or 32).
// MODE 0/3: triple-buffered counted-vmcnt pipeline (2 stages in flight).
// MODE 2: lm_head fallback (XCD swizzle + B reg-staged from f32, BK=32).
// MODE 4: lm_head best-measured (round-8): XCD swizzle + bf16 B via GLD16,
//         single-buffered stage/sync/compute/sync loop, 32KB LDS.
// EPI: 0=store f32(+bias), 1=f32 += residual (atomic when SK>1),
//      2=bf16 gelu(+bias), 4=bf16 per-head scatter
// SK: split-K factor (blockIdx.z selects split; bias applied by split 0)
template <int EPI, int MODE, int BM, int BN, int BK, int SK>
__global__ __launch_bounds__(256) void gemm_bf16_kernel(
    const u16* __restrict__ A, const u16* __restrict__ A2,
    const u16* __restrict__ B, const u16* __restrict__ B2,
    const float* __restrict__ bias, const float* __restrict__ bias2,
    const float* __restrict__ bias3, float* __restrict__ Cm,
    int K, int ldc, int whichbase) {
  constexpr int WM = BM / 2, WN = BN / 2, MF = WM / 16, NF = WN / 16;
  constexpr int KS = BK / 32;
  constexpr int NB = BK / 8;
  constexpr int PA = BM * BK / 2048;
  constexpr int PB = BN * BK / 2048;
  constexpr int RPP = 2048 / BK;
  constexpr int NBUF = (MODE == 2) ? 2 : (MODE == 4 ? 1 : 3);
  __shared__ u16 As[NBUF][BM * BK];
  __shared__ u16 Bs[NBUF][BN * BK];
  int tid = threadIdx.x;
  int lane = tid & 63, wave = tid >> 6;
  int wr = wave >> 1, wc = wave & 1;
  int row0, col0;
  bool isq = true;
  const u16* Ause = A;
  const u16* Buse = B;
  if (MODE == 2 || MODE == 4) {
    int id = blockIdx.x;                 // 0..1999
    int wg = (id & 7) * 250 + (id >> 3); // bijective XCD swizzle
    row0 = (wg & 7) * BM;
    col0 = (wg >> 3) * BN;
  } else if (MODE == 3) {
    int bx = blockIdx.x;
    isq = bx < (1024 / BN);
    Ause = isq ? A : A2;
    Buse = isq ? B : B2;
    col0 = (isq ? bx : bx - 1024 / BN) * BN;
    row0 = blockIdx.y * BM;
  } else {
    row0 = blockIdx.y * BM;
    col0 = blockIdx.x * BN;
  }
  const int split = (SK > 1) ? blockIdx.z : 0;
  const int Kloc = K / SK;
  const int kbase = split * Kloc;
  f32x4 acc[MF][NF];
#pragma unroll
  for (int m = 0; m < MF; ++m)
#pragma unroll
    for (int n = 0; n < NF; ++n) acc[m][n] = (f32x4){0.f, 0.f, 0.f, 0.f};

  int srow = tid / NB;
  int sblk = (BK == 64) ? ((tid & 7) ^ ((tid >> 3) & 7))
                        : ((tid & 3) ^ ((tid >> 3) & 3));
  const u16* Ab = Ause + (size_t)row0 * K + kbase;
  int arow = wr * WM + (lane & 15);
  int brow = wc * WN + (lane & 15);
  int g8 = lane >> 4;
  const int NT = Kloc / BK;

  auto compute = [&](const u16* Ac, const u16* Bc) {
#pragma unroll
    for (int ks = 0; ks < KS; ++ks) {
      short8 af[MF], bg[NF];
#pragma unroll
      for (int m = 0; m < MF; ++m) {
        int row = arow + m * 16;
        int off = (BK == 64) ? row * 64 + (((ks * 4 + g8) ^ (row & 7)) << 3)
                             : row * 32 + ((g8 ^ ((row >> 1) & 3)) << 3);
        af[m] = *(const short8*)&Ac[off];
      }
#pragma unroll
      for (int n = 0; n < NF; ++n) {
        int row = brow + n * 16;
        int off = (BK == 64) ? row * 64 + (((ks * 4 + g8) ^ (row & 7)) << 3)
                             : row * 32 + ((g8 ^ ((row >> 1) & 3)) << 3);
        bg[n] = *(const short8*)&Bc[off];
      }
      __builtin_amdgcn_s_setprio(1);
#pragma unroll
      for (int m = 0; m < MF; ++m)
#pragma unroll
        for (int n = 0; n < NF; ++n)
          acc[m][n] = MFMA(af[m], bg[n], acc[m][n]);
      __builtin_amdgcn_s_setprio(0);
    }
  };

  if constexpr (MODE == 2) {
    // B reg-staged from f32 (wte is [N][K] f32), BK=32 fallback
    const float* Bf = (const float*)B;
    int bsr = tid >> 2;                  // 0..63 (row within 64-row pass)
    int bkb = tid & 3;                   // 8-k block
    float4 rb0, rb1, rb2, rb3;
    auto loadB = [&](int k0) {
      const float* p0 = Bf + (size_t)(col0 + bsr) * 1024 + k0 + bkb * 8;
      const float* p1 = Bf + (size_t)(col0 + 64 + bsr) * 1024 + k0 + bkb * 8;
      rb0 = *(const float4*)p0; rb1 = *(const float4*)(p0 + 4);
      rb2 = *(const float4*)p1; rb3 = *(const float4*)(p1 + 4);
    };
    auto writeB = [&](int bufi) {
      u16 t0[8] = {f2bf(rb0.x), f2bf(rb0.y), f2bf(rb0.z), f2bf(rb0.w),
                   f2bf(rb1.x), f2bf(rb1.y), f2bf(rb1.z), f2bf(rb1.w)};
      u16 t1[8] = {f2bf(rb2.x), f2bf(rb2.y), f2bf(rb2.z), f2bf(rb2.w),
                   f2bf(rb3.x), f2bf(rb3.y), f2bf(rb3.z), f2bf(rb3.w)};
      int r1 = 64 + bsr;
      *(short8*)&Bs[bufi][bsr * 32 + ((bkb ^ ((bsr >> 1) & 3)) << 3)] = *(short8*)t0;
      *(short8*)&Bs[bufi][r1 * 32 + ((bkb ^ ((r1 >> 1) & 3)) << 3)] = *(short8*)t1;
    };
    auto stageA = [&](int bufi, int k0) {
#pragma unroll
      for (int p = 0; p < PA; ++p)
        GLD16(Ab + (size_t)(p * RPP + srow) * K + k0 + sblk * 8,
              &As[bufi][p * 2048 + wave * 512]);
    };
    loadB(0);
    stageA(0, 0);
    writeB(0);
    __syncthreads();
    for (int t = 0; t < NT; ++t) {
      int cur = t & 1;
      if (t + 1 < NT) { loadB((t + 1) * BK); stageA(cur ^ 1, (t + 1) * BK); }
      compute(As[cur], Bs[cur]);
      if (t + 1 < NT) writeB(cur ^ 1);   // cvt+ds_write after MFMAs (T14)
      __syncthreads();
    }
  } else if constexpr (MODE == 4) {
    // round-8 structure: single-buffered, GLD16 both operands (bf16 B)
    const u16* Bb = Buse + (size_t)col0 * K + kbase;
    for (int t = 0; t < NT; ++t) {
      int k0 = t * BK;
#pragma unroll
      for (int p = 0; p < PA; ++p)
        GLD16(Ab + (size_t)(p * RPP + srow) * K + k0 + sblk * 8,
              &As[0][p * 2048 + wave * 512]);
#pragma unroll
      for (int p = 0; p < PB; ++p)
        GLD16(Bb + (size_t)(p * RPP + srow) * K + k0 + sblk * 8,
              &Bs[0][p * 2048 + wave * 512]);
      __syncthreads();            // compiler drains vmcnt here
      compute(As[0], Bs[0]);
      __syncthreads();
    }
  } else {
    const u16* Bb = Buse + (size_t)col0 * K + kbase;
    auto stage = [&](int bufi, int k0) {
#pragma unroll
      for (int p = 0; p < PA; ++p)
        GLD16(Ab + (size_t)(p * RPP + srow) * K + k0 + sblk * 8,
              &As[bufi][p * 2048 + wave * 512]);
#pragma unroll
      for (int p = 0; p < PB; ++p)
        GLD16(Bb + (size_t)(p * RPP + srow) * K + k0 + sblk * 8,
              &Bs[bufi][p * 2048 + wave * 512]);
    };
    // T4 pipeline: 2 stages in flight, counted vmcnt, raw barriers.
    stage(0, 0);
    if (NT > 1) stage(1, BK);
    for (int t = 0; t < NT; ++t) {
      if (t + 1 < NT) waitcnt_vm<PA + PB>();  // tile t resident; t+1 in flight
      else            waitcnt_vm<0>();        // final drain
      __builtin_amdgcn_s_barrier();
      __builtin_amdgcn_sched_barrier(0);
      if (t + 2 < NT) stage((t + 2) % 3, (t + 2) * BK);
      int cur = t % 3;
      compute(As[cur], Bs[cur]);
      // no trailing barrier: 3 buffers + next-iter barrier protect reuse
    }
  }

  int r0 = row0 + wr * WM + g8 * 4;
  int c0 = col0 + wc * WN + (lane & 15);

  if (EPI == 4) {
    // scatter to per-head layouts: q/k [bh][t][d], v [bh][d][t]
    u16* qb = (u16*)Cm;
#pragma unroll
    for (int m = 0; m < MF; ++m)
#pragma unroll
      for (int n = 0; n < NF; ++n) {
        int j = c0 + n * 16;
        int which = (MODE == 3 ? (isq ? 0 : 1) : whichbase) + (j >> 10);
        const float* bp = which == 0 ? bias : (which == 1 ? bias2 : bias3);
        float bj = bp ? bp[j & 1023] : 0.0f;
        int h = (j & 1023) >> 6, d = j & 63;
        int trow0 = r0 + m * 16;
        int b = trow0 >> 9, t0 = trow0 & 511;
        int bh = b * 16 + h;
        u16 vals[4];
#pragma unroll
        for (int r = 0; r < 4; ++r) vals[r] = f2bf(acc[m][n][r] + bj);
        if (which < 2) {
          u16* dst = qb + (size_t)which * 1048576 + (size_t)bh * 32768 + (size_t)t0 * 64 + d;
#pragma unroll
          for (int r = 0; r < 4; ++r) dst[(size_t)r * 64] = vals[r];
        } else {
          u16* dst = qb + 2 * 1048576 + (size_t)bh * 32768 + (size_t)d * 512 + t0;
          *(ushort4*)dst = *(ushort4*)vals;
        }
      }
    return;
  }

  float bj[NF];
#pragma unroll
  for (int n = 0; n < NF; ++n)
    bj[n] = bias ? bias[c0 + n * 16] : 0.0f;
  u16* Cb = (u16*)Cm;
#pragma unroll
  for (int m = 0; m < MF; ++m)
#pragma unroll
    for (int n = 0; n < NF; ++n)
#pragma unroll
      for (int r = 0; r < 4; ++r) {
        size_t off = (size_t)(r0 + m * 16 + r) * ldc + c0 + n * 16;
        float v = acc[m][n][r] + ((SK == 1 || split == 0) ? bj[n] : 0.0f);
        if (EPI == 0) Cm[off] = v;
        else if (EPI == 1) {
          if constexpr (SK > 1) atomicAdd(&Cm[off], v);
          else Cm[off] += v;
        }
        else if (EPI == 2) Cb[off] = f2bf(gelu_f(v));
      }
}

// ---------------- fused flash attention (causal, incl. cross per ref) ----
// q,k: [32 bh][512 t][64 d] bf16;  v: [32 bh][64 d][512 t] bf16
// y: [1024 tok][1024 C] bf16.  Grid (16 q-tiles, 32 bh), 256 threads.
__global__ __launch_bounds__(256) void attn_kernel(
    const u16* __restrict__ qh, const u16* __restrict__ kh,
    const u16* __restrict__ vt, u16* __restrict__ y) {
  __shared__ u16 P[32 * 512];             // swizzled probs
  __shared__ float smax[4][32], ssum[4][32];
  int tid = threadIdx.x, lane = tid & 63, w = tid >> 6;
  int bx = blockIdx.x, bh = blockIdx.y;
  int q0 = bx * 32;
  int b = bh >> 4, h = bh & 15;
  const u16* qb = qh + (size_t)bh * 32768;
  const u16* kb = kh + (size_t)bh * 32768;
  const u16* vb = vt + (size_t)bh * 32768;
  int g = lane >> 4, c = lane & 15;

  short8 a[2][2];
#pragma unroll
  for (int rt = 0; rt < 2; ++rt)
#pragma unroll
    for (int ks = 0; ks < 2; ++ks)
      a[rt][ks] = *(const short8*)(qb + (size_t)(q0 + rt * 16 + c) * 64 + ks * 32 + g * 8);

  int lim = q0 + 31;
  int nct = (lim - w * 128) / 16 + 1;
  if (nct > 8) nct = 8;
  if (nct < 0) nct = 0;
  f32x4 s[2][8];
#pragma unroll
  for (int rt = 0; rt < 2; ++rt)
#pragma unroll
    for (int ct = 0; ct < 8; ++ct) s[rt][ct] = (f32x4){0.f, 0.f, 0.f, 0.f};
  for (int ct = 0; ct < nct; ++ct) {
    int n0 = w * 128 + ct * 16;
#pragma unroll
    for (int ks = 0; ks < 2; ++ks) {
      short8 bf = *(const short8*)(kb + (size_t)(n0 + c) * 64 + ks * 32 + g * 8);
      s[0][ct] = MFMA(a[0][ks], bf, s[0][ct]);
      s[1][ct] = MFMA(a[1][ks], bf, s[1][ct]);
    }
  }

  float mx[2][4];
#pragma unroll
  for (int rt = 0; rt < 2; ++rt)
#pragma unroll
    for (int r = 0; r < 4; ++r) mx[rt][r] = -1e30f;
  for (int ct = 0; ct < nct; ++ct) {
    int col = w * 128 + ct * 16 + c;
#pragma unroll
    for (int rt = 0; rt < 2; ++rt)
#pragma unroll
      for (int r = 0; r < 4; ++r) {
        int trow = q0 + rt * 16 + g * 4 + r;
        float v = s[rt][ct][r] * QKSCALE;
        if (col > trow) v = -1e30f;
        s[rt][ct][r] = v;
        mx[rt][r] = fmaxf(mx[rt][r], v);
      }
  }
#pragma unroll
  for (int off = 1; off < 16; off <<= 1)
#pragma unroll
    for (int rt = 0; rt < 2; ++rt)
#pragma unroll
      for (int r = 0; r < 4; ++r) mx[rt][r] = fmaxf(mx[rt][r], __shfl_xor(mx[rt][r], off));
  if (c == 0)
#pragma unroll
    for (int rt = 0; rt < 2; ++rt)
#pragma unroll
      for (int r = 0; r < 4; ++r) smax[w][rt * 16 + g * 4 + r] = mx[rt][r];
  __syncthreads();

  float m_[2][4], sum[2][4];
#pragma unroll
  for (int rt = 0; rt < 2; ++rt)
#pragma unroll
    for (int r = 0; r < 4; ++r) {
      int row = rt * 16 + g * 4 + r;
      m_[rt][r] = fmaxf(fmaxf(smax[0][row], smax[1][row]), fmaxf(smax[2][row], smax[3][row]));
      sum[rt][r] = 0.f;
    }
  for (int ct = 0; ct < nct; ++ct) {
    int col = w * 128 + ct * 16 + c;
    int blk = col >> 3, cl = col & 7;
#pragma unroll
    for (int rt = 0; rt < 2; ++rt)
#pragma unroll
      for (int r = 0; r < 4; ++r) {
        float p = __expf(s[rt][ct][r] - m_[rt][r]);
        sum[rt][r] += p;
        int row = rt * 16 + g * 4 + r;
        int hsh = (row ^ (row >> 2)) & 7;
        P[row * 512 + ((blk ^ hsh) << 3) + cl] = f2bf(p);
      }
  }
#pragma unroll
  for (int off = 1; off < 16; off <<= 1)
#pragma unroll
    for (int rt = 0; rt < 2; ++rt)
#pragma unroll
      for (int r = 0; r < 4; ++r) sum[rt][r] += __shfl_xor(sum[rt][r], off);
  if (c == 0)
#pragma unroll
    for (int rt = 0; rt < 2; ++rt)
#pragma unroll
      for (int r = 0; r < 4; ++r) ssum[w][rt * 16 + g * 4 + r] = sum[rt][r];
  __syncthreads();

  float li[2][4];
#pragma unroll
  for (int rt = 0; rt < 2; ++rt)
#pragma unroll
    for (int r = 0; r < 4; ++r) {
      int row = rt * 16 + g * 4 + r;
      li[rt][r] = 1.0f / (ssum[0][row] + ssum[1][row] + ssum[2][row] + ssum[3][row]);
    }

  int rt2 = w >> 1, nh = w & 1;
  f32x4 o[2];
  o[0] = (f32x4){0.f, 0.f, 0.f, 0.f};
  o[1] = (f32x4){0.f, 0.f, 0.f, 0.f};
  int nks = bx + 1;
  int prow = rt2 * 16 + c;
  int phsh = (prow ^ (prow >> 2)) & 7;
  for (int ks = 0; ks < nks; ++ks) {
    short8 pa = *(const short8*)&P[prow * 512 + (((ks * 4 + g) ^ phsh) << 3)];
#pragma unroll
    for (int nt = 0; nt < 2; ++nt) {
      int d = nh * 32 + nt * 16 + c;
      short8 vf = *(const short8*)(vb + (size_t)d * 512 + ks * 32 + g * 8);
      o[nt] = MFMA(pa, vf, o[nt]);
    }
  }
#pragma unroll
  for (int nt = 0; nt < 2; ++nt)
#pragma unroll
    for (int r = 0; r < 4; ++r) {
      int trow = q0 + rt2 * 16 + g * 4 + r;
      float val = o[nt][r] * li[rt2][r];
      y[(size_t)(b * 512 + trow) * 1024 + h * 64 + nh * 32 + nt * 16 + c] = f2bf(val);
    }
}

// ---------------- launch ---------------------------------------------------
extern "C" void kernel_launch(void* const* d_in, const int* in_sizes, int n_in,
                              void* d_out, int out_size, void* d_ws, size_t ws_size,
                              hipStream_t stream) {
  const int*   idx   = (const int*)d_in[0];
  const float* xa    = (const float*)d_in[1];
  const float* wte   = (const float*)d_in[2];
  const float* wpe   = (const float*)d_in[3];
  const float* ln1_w = (const float*)d_in[4];
  const float* ln1_b = (const float*)d_in[5];
  const float* sa_wq = (const float*)d_in[6];
  const float* sa_bq = (const float*)d_in[7];
  const float* sa_wk = (const float*)d_in[8];
  const float* sa_bk = (const float*)d_in[9];
  const float* sa_wv = (const float*)d_in[10];
  const float* sa_bv = (const float*)d_in[11];
  const float* sa_wo = (const float*)d_in[12];
  const float* sa_bo = (const float*)d_in[13];
  const float* ca_wq = (const float*)d_in[14];
  const float* ca_bq = (const float*)d_in[15];
  const float* ca_wk = (const float*)d_in[16];
  const float* ca_bk = (const float*)d_in[17];
  const float* ca_wv = (const float*)d_in[18];
  const float* ca_bv = (const float*)d_in[19];
  const float* ca_wo = (const float*)d_in[20];
  const float* ca_bo = (const float*)d_in[21];
  const float* ln2_w = (const float*)d_in[22];
  const float* ln2_b = (const float*)d_in[23];
  const float* fc_w  = (const float*)d_in[24];
  const float* fc_b  = (const float*)d_in[25];
  const float* pr_w  = (const float*)d_in[26];
  const float* pr_b  = (const float*)d_in[27];
  const float* lnf_w = (const float*)d_in[28];
  const float* lnf_b = (const float*)d_in[29];

  const size_t M1 = 1048576;
  float* ws     = (float*)d_ws;
  float* x      = ws;                    // [1024,1024] f32  (4 MB)
  u16* qkvh  = (u16*)(x + M1);           // q,k: [32][512][64]; v: [32][64][512]
  u16* nbf   = qkvh + 3 * M1;            // [1024,1024] bf16
  u16* ybf   = nbf + M1;                 // [1024,1024] bf16
  u16* hmbf  = ybf + M1;                 // [1024,4096] bf16
  u16* xabf  = hmbf + 4 * M1;            // [1024,1024] bf16

  // base (24.75 MB) + optional wtebf (64 MB) + wT (32 MB or 192 MB)
  // fullW mode: base + wtebf + 6-layer wT = 292,028,416 B
  const bool fullW = ws_size >= 292028416ull;
  const bool full  = fullW || ws_size >= 226492416ull;
  u16* wtebf = xabf + M1;                          // only valid if fullW
  u16* wT    = fullW ? wtebf + (size_t)VV * CC : xabf + M1;
  const size_t wls = full ? 16 * M1 : 0;           // wT layer stride (elems)

  const size_t oQKV = 0, oWO = 3 * M1, oCQ = 4 * M1, oCKV = 5 * M1,
               oCWO = 7 * M1, oFC = 8 * M1, oPR = 12 * M1;

  embed_kernel<<<NTOK, 256, 0, stream>>>(idx, wte, wpe, x);
  convbf_kernel<<<(NTOK * CC / 4 + 255) / 256, 256, 0, stream>>>(xa, xabf, NTOK * CC / 4);
  if (fullW)
    convbf_kernel<<<(VV * CC / 4 + 255) / 256, 256, 0, stream>>>(wte, wtebf, VV * CC / 4);
  if (full)   // all 6 layers' weight prep in ONE saturated dispatch
    wtransL_kernel<<<dim3(16, 16, 96), 256, 0, stream>>>(
        sa_wq, sa_wk, sa_wv, sa_wo, ca_wq, ca_wk, ca_wv, ca_wo,
        fc_w, pr_w, wT, wls, 0);

  for (int l = 0; l < 6; ++l) {
    size_t bofs = (size_t)l * CC;
    u16* wTl = wT + (size_t)l * wls;

    if (!full)
      wtransL_kernel<<<dim3(16, 16, 16), 256, 0, stream>>>(
          sa_wq, sa_wk, sa_wv, sa_wo, ca_wq, ca_wk, ca_wv, ca_wo,
          fc_w, pr_w, wT, 0, l);

    // ---- self attention ----
    ln_kernel<<<NTOK, 256, 0, stream>>>(x, ln1_w + bofs, ln1_b + bofs, nbf);
    gemm_bf16_kernel<4, 0, 64, 128, 64, 1><<<dim3(24, 16), 256, 0, stream>>>(
        nbf, nullptr, wTl + oQKV, nullptr, sa_bq + bofs, sa_bk + bofs,
        sa_bv + bofs, (float*)qkvh, CC, 0, 0);
    attn_kernel<<<dim3(16, 32), 256, 0, stream>>>(qkvh, qkvh + M1, qkvh + 2 * M1, ybf);
    gemm_bf16_kernel<1, 0, 32, 64, 64, 2><<<dim3(16, 32, 2), 256, 0, stream>>>(
        ybf, nullptr, wTl + oWO, nullptr, sa_bo + bofs, nullptr, nullptr,
        x, CC, CC, 0);

    // ---- cross attention: cq | ckv merged (independent inputs) ----
    ln_kernel<<<NTOK, 256, 0, stream>>>(x, ln1_w + bofs, ln1_b + bofs, nbf);
    gemm_bf16_kernel<4, 3, 64, 64, 64, 1><<<dim3(48, 16), 256, 0, stream>>>(
        nbf, xabf, wTl + oCQ, wTl + oCKV, ca_bq + bofs, ca_bk + bofs,
        ca_bv + bofs, (float*)qkvh, CC, 0, 0);
    attn_kernel<<<dim3(16, 32), 256, 0, stream>>>(qkvh, qkvh + M1, qkvh + 2 * M1, ybf);
    gemm_bf16_kernel<1, 0, 32, 64, 64, 2><<<dim3(16, 32, 2), 256, 0, stream>>>(
        ybf, nullptr, wTl + oCWO, nullptr, ca_bo + bofs, nullptr, nullptr,
        x, CC, CC, 0);

    // ---- MLP ----
    ln_kernel<<<NTOK, 256, 0, stream>>>(x, ln2_w + bofs, ln2_b + bofs, nbf);
    gemm_bf16_kernel<2, 0, 64, 128, 64, 1><<<dim3(32, 16), 256, 0, stream>>>(
        nbf, nullptr, wTl + oFC, nullptr, fc_b + (size_t)l * DFF_, nullptr,
        nullptr, (float*)hmbf, CC, DFF_, 0);
    gemm_bf16_kernel<1, 0, 32, 64, 64, 4><<<dim3(16, 32, 4), 256, 0, stream>>>(
        hmbf, nullptr, wTl + oPR, nullptr, pr_b + bofs, nullptr, nullptr,
        x, DFF_, CC, 0);
  }

  // ---- final LN + tied lm_head ----
  ln_kernel<<<NTOK, 256, 0, stream>>>(x, lnf_w, lnf_b, nbf);
  if (fullW)   // best-measured round-8 path: bf16 B, BK=64 single-buf
    gemm_bf16_kernel<0, 4, 128, 128, 64, 1><<<dim3(2000), 256, 0, stream>>>(
        nbf, nullptr, wtebf, nullptr, nullptr, nullptr, nullptr,
        (float*)d_out, CC, VV, 0);
  else         // fallback: f32 B reg-staged, BK=32
    gemm_bf16_kernel<0, 2, 128, 128, 32, 1><<<dim3(2000), 256, 0, stream>>>(
        nbf, nullptr, (const u16*)wte, nullptr, nullptr, nullptr, nullptr,
        (float*)d_out, CC, VV, 0);
}

// Round 18
// 1487.139 us; speedup vs baseline: 1.0542x; 1.0150x over previous
//
#include <hip/hip_runtime.h>
#include <math.h>

#define CC   1024
#define HH   16
#define DH   64
#define TT   512
#define NTOK 1024     // B*T
#define DFF_ 4096
#define VV   32000
#define QKSCALE 0.125f   // 1/sqrt(64)

typedef unsigned short u16;
typedef __attribute__((ext_vector_type(8))) short short8;
typedef __attribute__((ext_vector_type(4))) float f32x4;

__device__ __forceinline__ u16 f2bf(float f) {   // RNE fp32->bf16
  union { float f; unsigned u; } v; v.f = f;
  unsigned r = v.u + 0x7FFFu + ((v.u >> 16) & 1u);
  return (u16)(r >> 16);
}
__device__ __forceinline__ float gelu_f(float h) {
  return 0.5f * h * (1.0f + tanhf(0.7978845608028654f * (h + 0.044715f * h * h * h)));
}

// counted vmcnt wait (immediate must be literal in asm string)
template <int N> __device__ __forceinline__ void waitcnt_vm() {
  if constexpr (N == 0) asm volatile("s_waitcnt vmcnt(0)" ::: "memory");
  else if constexpr (N == 1) asm volatile("s_waitcnt vmcnt(1)" ::: "memory");
  else if constexpr (N == 2) asm volatile("s_waitcnt vmcnt(2)" ::: "memory");
  else if constexpr (N == 3) asm volatile("s_waitcnt vmcnt(3)" ::: "memory");
  else if constexpr (N == 4) asm volatile("s_waitcnt vmcnt(4)" ::: "memory");
  else if constexpr (N == 5) asm volatile("s_waitcnt vmcnt(5)" ::: "memory");
  else if constexpr (N == 6) asm volatile("s_waitcnt vmcnt(6)" ::: "memory");
  else if constexpr (N == 7) asm volatile("s_waitcnt vmcnt(7)" ::: "memory");
  else if constexpr (N == 8) asm volatile("s_waitcnt vmcnt(8)" ::: "memory");
  else static_assert(N <= 8, "unsupported vmcnt");
}

// async global->LDS, 16B per lane; dest = wave-uniform base + lane*16
#define GLD16(gp, lp) __builtin_amdgcn_global_load_lds( \
    (const __attribute__((address_space(1))) void*)(gp), \
    (__attribute__((address_space(3))) void*)(lp), 16, 0, 0)

#define MFMA(a, b, c) __builtin_amdgcn_mfma_f32_16x16x32_bf16(a, b, c, 0, 0, 0)

// ---------------- embedding ----------------------------------------------
__global__ __launch_bounds__(256) void embed_kernel(
    const int* __restrict__ idx, const float* __restrict__ wte,
    const float* __restrict__ wpe, float* __restrict__ x) {
  int row = blockIdx.x;
  int t = row & (TT - 1);
  int id = idx[row];
  const float4* a = (const float4*)(wte + (size_t)id * CC);
  const float4* p = (const float4*)(wpe + (size_t)t * CC);
  float4* o = (float4*)(x + (size_t)row * CC);
  int c = threadIdx.x;
  float4 va = a[c], vp = p[c];
  float4 ov;
  ov.x = va.x + vp.x; ov.y = va.y + vp.y; ov.z = va.z + vp.z; ov.w = va.w + vp.w;
  o[c] = ov;
}

// ---------------- layernorm (fp32 in -> bf16 out) ------------------------
__global__ __launch_bounds__(256) void ln_kernel(
    const float* __restrict__ x, const float* __restrict__ w,
    const float* __restrict__ b, u16* __restrict__ out) {
  int row = blockIdx.x, tid = threadIdx.x;
  float4 v = ((const float4*)(x + (size_t)row * CC))[tid];
  float s  = v.x + v.y + v.z + v.w;
  float sq = fmaf(v.x, v.x, fmaf(v.y, v.y, fmaf(v.z, v.z, v.w * v.w)));
  for (int o = 32; o > 0; o >>= 1) { s += __shfl_down(s, o); sq += __shfl_down(sq, o); }
  __shared__ float rs[4], rq[4];
  int wid = tid >> 6, lane = tid & 63;
  if (lane == 0) { rs[wid] = s; rq[wid] = sq; }
  __syncthreads();
  s  = rs[0] + rs[1] + rs[2] + rs[3];
  sq = rq[0] + rq[1] + rq[2] + rq[3];
  float mean = s * (1.0f / CC);
  float var  = sq * (1.0f / CC) - mean * mean;
  float rstd = 1.0f / sqrtf(var + 1e-5f);
  float4 wv = ((const float4*)w)[tid];
  float4 bv = ((const float4*)b)[tid];
  ushort4 o;
  o.x = f2bf((v.x - mean) * rstd * wv.x + bv.x);
  o.y = f2bf((v.y - mean) * rstd * wv.y + bv.y);
  o.z = f2bf((v.z - mean) * rstd * wv.z + bv.z);
  o.w = f2bf((v.w - mean) * rstd * wv.w + bv.w);
  ((ushort4*)(out + (size_t)row * CC))[tid] = o;
}

// ---------------- weight prep: transposes + wte convert ------------------
// z < NL*16: per-layer transposes (slot 0-7 squares; 8-11 fc; 12-15 pr)
// z >= NL*16 (fullW only): 32 slots of grid-stride wte f32->bf16 convert
__global__ __launch_bounds__(256) void wtransL_kernel(
    const float* __restrict__ w0, const float* __restrict__ w1,
    const float* __restrict__ w2, const float* __restrict__ w3,
    const float* __restrict__ w4, const float* __restrict__ w5,
    const float* __restrict__ w6, const float* __restrict__ w7,
    const float* __restrict__ fc, const float* __restrict__ pr,
    u16* __restrict__ wt, size_t dls, int lbase, int nl,
    const float* __restrict__ wte, u16* __restrict__ wtebf) {
  const size_t M1 = 1048576;
  int z = blockIdx.z;
  if (z >= nl * 16) {
    // wte f32 -> bf16, grid-stride over 8,192,000 float4s
    int slot = z - nl * 16;                       // 0..31
    int blin = blockIdx.y * 16 + blockIdx.x;      // 0..255
    const int n4 = VV * CC / 4;
    int gi = (slot * 256 + blin) * 256 + threadIdx.x;
    for (int i = gi; i < n4; i += 32 * 256 * 256) {
      float4 v = ((const float4*)wte)[i];
      ushort4 o; o.x = f2bf(v.x); o.y = f2bf(v.y); o.z = f2bf(v.z); o.w = f2bf(v.w);
      ((ushort4*)wtebf)[i] = o;
    }
    return;
  }
  int l = lbase + (z >> 4), slot = z & 15;
  size_t wofs = (size_t)l * M1;          // square weights: l*C*C
  size_t mofs = (size_t)l * 4 * M1;      // fc/pr: l*C*DFF
  const float* src;
  size_t doff = (size_t)(l - lbase) * dls;
  int sstr, dstr;
  if (slot < 8) {
    const float* base = slot == 0 ? w0 : slot == 1 ? w1 : slot == 2 ? w2
                      : slot == 3 ? w3 : slot == 4 ? w4 : slot == 5 ? w5
                      : slot == 6 ? w6 : w7;
    src = base + wofs; sstr = 1024; doff += (size_t)slot * M1; dstr = 1024;
  } else if (slot < 12) {
    int s = slot - 8;
    src = fc + mofs + (size_t)s * 1024; sstr = 4096;
    doff += 8 * M1 + (size_t)s * M1; dstr = 1024;
  } else {
    int s = slot - 12;
    src = pr + mofs + (size_t)s * M1; sstr = 1024;
    doff += 12 * M1 + (size_t)s * 1024; dstr = 4096;
  }
  __shared__ float t[64][65];
  int bx = blockIdx.x * 64, by = blockIdx.y * 64;
  int tid = threadIdx.x;
  int r16 = tid >> 4;          // 0..15
  int c4  = (tid & 15) * 4;    // 0..60
#pragma unroll
  for (int i = 0; i < 4; ++i) {
    int row = r16 + i * 16;
    float4 v = *(const float4*)&src[(size_t)(by + row) * sstr + bx + c4];
    t[row][c4] = v.x; t[row][c4 + 1] = v.y; t[row][c4 + 2] = v.z; t[row][c4 + 3] = v.w;
  }
  __syncthreads();
#pragma unroll
  for (int i = 0; i < 4; ++i) {
    int orow = r16 + i * 16;   // output row n = bx+orow; k = by+c4..+3
    ushort4 o;
    o.x = f2bf(t[c4 + 0][orow]);
    o.y = f2bf(t[c4 + 1][orow]);
    o.z = f2bf(t[c4 + 2][orow]);
    o.w = f2bf(t[c4 + 3][orow]);
    *(ushort4*)&wt[doff + (size_t)(bx + orow) * dstr + by + c4] = o;
  }
}

// ---------------- elementwise f32 -> bf16 --------------------------------
__global__ __launch_bounds__(256) void convbf_kernel(
    const float* __restrict__ in, u16* __restrict__ out, int n4) {
  int i = blockIdx.x * 256 + threadIdx.x;
  if (i < n4) {
    float4 v = ((const float4*)in)[i];
    ushort4 o; o.x = f2bf(v.x); o.y = f2bf(v.y); o.z = f2bf(v.z); o.w = f2bf(v.w);
    ((ushort4*)out)[i] = o;
  }
}

// ---------------- bf16 MFMA GEMM, XOR-swizzled LDS -----------------------
// C[M,N](ldc) = epi(A[M,K] @ B^T + bias);  A[M,K], B[N,K] bf16 row-major.
// MODE 0/3: triple-buffered counted-vmcnt pipeline (2 stages in flight).
// MODE 2: lm_head fallback (XCD swizzle + B reg-staged from f32, BK=32).
// MODE 4: lm_head best-measured: XCD swizzle + bf16 B via GLD16,
//         single-buffered stage/sync/compute/sync loop, 32KB LDS.
// EPI: 0=store f32(+bias), 1=f32 += residual (atomic when SK>1),
//      2=bf16 gelu(+bias), 4=bf16 per-head scatter
// SK: split-K factor (blockIdx.z selects split; bias applied by split 0)
template <int EPI, int MODE, int BM, int BN, int BK, int SK>
__global__ __launch_bounds__(256) void gemm_bf16_kernel(
    const u16* __restrict__ A, const u16* __restrict__ A2,
    const u16* __restrict__ B, const u16* __restrict__ B2,
    const float* __restrict__ bias, const float* __restrict__ bias2,
    const float* __restrict__ bias3, float* __restrict__ Cm,
    int K, int ldc, int whichbase) {
  constexpr int WM = BM / 2, WN = BN / 2, MF = WM / 16, NF = WN / 16;
  constexpr int KS = BK / 32;
  constexpr int NB = BK / 8;
  constexpr int PA = BM * BK / 2048;
  constexpr int PB = BN * BK / 2048;
  constexpr int RPP = 2048 / BK;
  constexpr int NBUF = (MODE == 2) ? 2 : (MODE == 4 ? 1 : 3);
  __shared__ u16 As[NBUF][BM * BK];
  __shared__ u16 Bs[NBUF][BN * BK];
  int tid = threadIdx.x;
  int lane = tid & 63, wave = tid >> 6;
  int wr = wave >> 1, wc = wave & 1;
  int row0, col0;
  bool isq = true;
  const u16* Ause = A;
  const u16* Buse = B;
  if (MODE == 2 || MODE == 4) {
    int id = blockIdx.x;                 // 0..1999
    int wg = (id & 7) * 250 + (id >> 3); // bijective XCD swizzle
    row0 = (wg & 7) * BM;
    col0 = (wg >> 3) * BN;
  } else if (MODE == 3) {
    int bx = blockIdx.x;
    isq = bx < (1024 / BN);
    Ause = isq ? A : A2;
    Buse = isq ? B : B2;
    col0 = (isq ? bx : bx - 1024 / BN) * BN;
    row0 = blockIdx.y * BM;
  } else {
    row0 = blockIdx.y * BM;
    col0 = blockIdx.x * BN;
  }
  const int split = (SK > 1) ? blockIdx.z : 0;
  const int Kloc = K / SK;
  const int kbase = split * Kloc;
  f32x4 acc[MF][NF];
#pragma unroll
  for (int m = 0; m < MF; ++m)
#pragma unroll
    for (int n = 0; n < NF; ++n) acc[m][n] = (f32x4){0.f, 0.f, 0.f, 0.f};

  int srow = tid / NB;
  int sblk = (BK == 64) ? ((tid & 7) ^ ((tid >> 3) & 7))
                        : ((tid & 3) ^ ((tid >> 3) & 3));
  const u16* Ab = Ause + (size_t)row0 * K + kbase;
  int arow = wr * WM + (lane & 15);
  int brow = wc * WN + (lane & 15);
  int g8 = lane >> 4;
  const int NT = Kloc / BK;

  auto compute = [&](const u16* Ac, const u16* Bc) {
#pragma unroll
    for (int ks = 0; ks < KS; ++ks) {
      short8 af[MF], bg[NF];
#pragma unroll
      for (int m = 0; m < MF; ++m) {
        int row = arow + m * 16;
        int off = (BK == 64) ? row * 64 + (((ks * 4 + g8) ^ (row & 7)) << 3)
                             : row * 32 + ((g8 ^ ((row >> 1) & 3)) << 3);
        af[m] = *(const short8*)&Ac[off];
      }
#pragma unroll
      for (int n = 0; n < NF; ++n) {
        int row = brow + n * 16;
        int off = (BK == 64) ? row * 64 + (((ks * 4 + g8) ^ (row & 7)) << 3)
                             : row * 32 + ((g8 ^ ((row >> 1) & 3)) << 3);
        bg[n] = *(const short8*)&Bc[off];
      }
      __builtin_amdgcn_s_setprio(1);
#pragma unroll
      for (int m = 0; m < MF; ++m)
#pragma unroll
        for (int n = 0; n < NF; ++n)
          acc[m][n] = MFMA(af[m], bg[n], acc[m][n]);
      __builtin_amdgcn_s_setprio(0);
    }
  };

  if constexpr (MODE == 2) {
    // B reg-staged from f32 (wte is [N][K] f32), BK=32 fallback
    const float* Bf = (const float*)B;
    int bsr = tid >> 2;                  // 0..63 (row within 64-row pass)
    int bkb = tid & 3;                   // 8-k block
    float4 rb0, rb1, rb2, rb3;
    auto loadB = [&](int k0) {
      const float* p0 = Bf + (size_t)(col0 + bsr) * 1024 + k0 + bkb * 8;
      const float* p1 = Bf + (size_t)(col0 + 64 + bsr) * 1024 + k0 + bkb * 8;
      rb0 = *(const float4*)p0; rb1 = *(const float4*)(p0 + 4);
      rb2 = *(const float4*)p1; rb3 = *(const float4*)(p1 + 4);
    };
    auto writeB = [&](int bufi) {
      u16 t0[8] = {f2bf(rb0.x), f2bf(rb0.y), f2bf(rb0.z), f2bf(rb0.w),
                   f2bf(rb1.x), f2bf(rb1.y), f2bf(rb1.z), f2bf(rb1.w)};
      u16 t1[8] = {f2bf(rb2.x), f2bf(rb2.y), f2bf(rb2.z), f2bf(rb2.w),
                   f2bf(rb3.x), f2bf(rb3.y), f2bf(rb3.z), f2bf(rb3.w)};
      int r1 = 64 + bsr;
      *(short8*)&Bs[bufi][bsr * 32 + ((bkb ^ ((bsr >> 1) & 3)) << 3)] = *(short8*)t0;
      *(short8*)&Bs[bufi][r1 * 32 + ((bkb ^ ((r1 >> 1) & 3)) << 3)] = *(short8*)t1;
    };
    auto stageA = [&](int bufi, int k0) {
#pragma unroll
      for (int p = 0; p < PA; ++p)
        GLD16(Ab + (size_t)(p * RPP + srow) * K + k0 + sblk * 8,
              &As[bufi][p * 2048 + wave * 512]);
    };
    loadB(0);
    stageA(0, 0);
    writeB(0);
    __syncthreads();
    for (int t = 0; t < NT; ++t) {
      int cur = t & 1;
      if (t + 1 < NT) { loadB((t + 1) * BK); stageA(cur ^ 1, (t + 1) * BK); }
      compute(As[cur], Bs[cur]);
      if (t + 1 < NT) writeB(cur ^ 1);   // cvt+ds_write after MFMAs (T14)
      __syncthreads();
    }
  } else if constexpr (MODE == 4) {
    // round-8 structure: single-buffered, GLD16 both operands (bf16 B)
    const u16* Bb = Buse + (size_t)col0 * K + kbase;
    for (int t = 0; t < NT; ++t) {
      int k0 = t * BK;
#pragma unroll
      for (int p = 0; p < PA; ++p)
        GLD16(Ab + (size_t)(p * RPP + srow) * K + k0 + sblk * 8,
              &As[0][p * 2048 + wave * 512]);
#pragma unroll
      for (int p = 0; p < PB; ++p)
        GLD16(Bb + (size_t)(p * RPP + srow) * K + k0 + sblk * 8,
              &Bs[0][p * 2048 + wave * 512]);
      __syncthreads();            // compiler drains vmcnt here
      compute(As[0], Bs[0]);
      __syncthreads();
    }
  } else {
    const u16* Bb = Buse + (size_t)col0 * K + kbase;
    auto stage = [&](int bufi, int k0) {
#pragma unroll
      for (int p = 0; p < PA; ++p)
        GLD16(Ab + (size_t)(p * RPP + srow) * K + k0 + sblk * 8,
              &As[bufi][p * 2048 + wave * 512]);
#pragma unroll
      for (int p = 0; p < PB; ++p)
        GLD16(Bb + (size_t)(p * RPP + srow) * K + k0 + sblk * 8,
              &Bs[bufi][p * 2048 + wave * 512]);
    };
    // T4 pipeline: 2 stages in flight, counted vmcnt, raw barriers.
    stage(0, 0);
    if (NT > 1) stage(1, BK);
    for (int t = 0; t < NT; ++t) {
      if (t + 1 < NT) waitcnt_vm<PA + PB>();  // tile t resident; t+1 in flight
      else            waitcnt_vm<0>();        // final drain
      __builtin_amdgcn_s_barrier();
      __builtin_amdgcn_sched_barrier(0);
      if (t + 2 < NT) stage((t + 2) % 3, (t + 2) * BK);
      int cur = t % 3;
      compute(As[cur], Bs[cur]);
      // no trailing barrier: 3 buffers + next-iter barrier protect reuse
    }
  }

  int r0 = row0 + wr * WM + g8 * 4;
  int c0 = col0 + wc * WN + (lane & 15);

  if (EPI == 4) {
    // scatter to per-head layouts: q/k [bh][t][d], v [bh][d][t]
    u16* qb = (u16*)Cm;
#pragma unroll
    for (int m = 0; m < MF; ++m)
#pragma unroll
      for (int n = 0; n < NF; ++n) {
        int j = c0 + n * 16;
        int which = (MODE == 3 ? (isq ? 0 : 1) : whichbase) + (j >> 10);
        const float* bp = which == 0 ? bias : (which == 1 ? bias2 : bias3);
        float bj = bp ? bp[j & 1023] : 0.0f;
        int h = (j & 1023) >> 6, d = j & 63;
        int trow0 = r0 + m * 16;
        int b = trow0 >> 9, t0 = trow0 & 511;
        int bh = b * 16 + h;
        u16 vals[4];
#pragma unroll
        for (int r = 0; r < 4; ++r) vals[r] = f2bf(acc[m][n][r] + bj);
        if (which < 2) {
          u16* dst = qb + (size_t)which * 1048576 + (size_t)bh * 32768 + (size_t)t0 * 64 + d;
#pragma unroll
          for (int r = 0; r < 4; ++r) dst[(size_t)r * 64] = vals[r];
        } else {
          u16* dst = qb + 2 * 1048576 + (size_t)bh * 32768 + (size_t)d * 512 + t0;
          *(ushort4*)dst = *(ushort4*)vals;
        }
      }
    return;
  }

  float bj[NF];
#pragma unroll
  for (int n = 0; n < NF; ++n)
    bj[n] = bias ? bias[c0 + n * 16] : 0.0f;
  u16* Cb = (u16*)Cm;
#pragma unroll
  for (int m = 0; m < MF; ++m)
#pragma unroll
    for (int n = 0; n < NF; ++n)
#pragma unroll
      for (int r = 0; r < 4; ++r) {
        size_t off = (size_t)(r0 + m * 16 + r) * ldc + c0 + n * 16;
        float v = acc[m][n][r] + ((SK == 1 || split == 0) ? bj[n] : 0.0f);
        if (EPI == 0) Cm[off] = v;
        else if (EPI == 1) {
          if constexpr (SK > 1) atomicAdd(&Cm[off], v);
          else Cm[off] += v;
        }
        else if (EPI == 2) Cb[off] = f2bf(gelu_f(v));
      }
}

// ---------------- fused flash attention (causal, incl. cross per ref) ----
// q,k: [32 bh][512 t][64 d] bf16;  v: [32 bh][64 d][512 t] bf16
// y: [1024 tok][1024 C] bf16.  Grid (8 paired q-tiles, 32 bh), 256 threads.
// Causal balance: block handles q-tiles {bx, 15-bx} (work i+1 -> 17/pair).
__global__ __launch_bounds__(256) void attn_kernel(
    const u16* __restrict__ qh, const u16* __restrict__ kh,
    const u16* __restrict__ vt, u16* __restrict__ y) {
  __shared__ u16 P[32 * 512];             // swizzled probs
  __shared__ float smax[4][32], ssum[4][32];
  int tid = threadIdx.x, lane = tid & 63, w = tid >> 6;
  int bh = blockIdx.y;
  int b = bh >> 4, h = bh & 15;
  const u16* qb = qh + (size_t)bh * 32768;
  const u16* kb = kh + (size_t)bh * 32768;
  const u16* vb = vt + (size_t)bh * 32768;
  int g = lane >> 4, c = lane & 15;

  for (int half = 0; half < 2; ++half) {
    int bx = half == 0 ? (int)blockIdx.x : 15 - (int)blockIdx.x;
    if (half) __syncthreads();            // protect P/smax/ssum reuse
    int q0 = bx * 32;

    short8 a[2][2];
#pragma unroll
    for (int rt = 0; rt < 2; ++rt)
#pragma unroll
      for (int ks = 0; ks < 2; ++ks)
        a[rt][ks] = *(const short8*)(qb + (size_t)(q0 + rt * 16 + c) * 64 + ks * 32 + g * 8);

    int lim = q0 + 31;
    int nct = (lim - w * 128) / 16 + 1;
    if (nct > 8) nct = 8;
    if (nct < 0) nct = 0;
    f32x4 s[2][8];
#pragma unroll
    for (int rt = 0; rt < 2; ++rt)
#pragma unroll
      for (int ct = 0; ct < 8; ++ct) s[rt][ct] = (f32x4){0.f, 0.f, 0.f, 0.f};
    for (int ct = 0; ct < nct; ++ct) {
      int n0 = w * 128 + ct * 16;
#pragma unroll
      for (int ks = 0; ks < 2; ++ks) {
        short8 bf = *(const short8*)(kb + (size_t)(n0 + c) * 64 + ks * 32 + g * 8);
        s[0][ct] = MFMA(a[0][ks], bf, s[0][ct]);
        s[1][ct] = MFMA(a[1][ks], bf, s[1][ct]);
      }
    }

    float mx[2][4];
#pragma unroll
    for (int rt = 0; rt < 2; ++rt)
#pragma unroll
      for (int r = 0; r < 4; ++r) mx[rt][r] = -1e30f;
    for (int ct = 0; ct < nct; ++ct) {
      int col = w * 128 + ct * 16 + c;
#pragma unroll
      for (int rt = 0; rt < 2; ++rt)
#pragma unroll
        for (int r = 0; r < 4; ++r) {
          int trow = q0 + rt * 16 + g * 4 + r;
          float v = s[rt][ct][r] * QKSCALE;
          if (col > trow) v = -1e30f;
          s[rt][ct][r] = v;
          mx[rt][r] = fmaxf(mx[rt][r], v);
        }
    }
#pragma unroll
    for (int off = 1; off < 16; off <<= 1)
#pragma unroll
      for (int rt = 0; rt < 2; ++rt)
#pragma unroll
        for (int r = 0; r < 4; ++r) mx[rt][r] = fmaxf(mx[rt][r], __shfl_xor(mx[rt][r], off));
    if (c == 0)
#pragma unroll
      for (int rt = 0; rt < 2; ++rt)
#pragma unroll
        for (int r = 0; r < 4; ++r) smax[w][rt * 16 + g * 4 + r] = mx[rt][r];
    __syncthreads();

    float m_[2][4], sum[2][4];
#pragma unroll
    for (int rt = 0; rt < 2; ++rt)
#pragma unroll
      for (int r = 0; r < 4; ++r) {
        int row = rt * 16 + g * 4 + r;
        m_[rt][r] = fmaxf(fmaxf(smax[0][row], smax[1][row]), fmaxf(smax[2][row], smax[3][row]));
        sum[rt][r] = 0.f;
      }
    for (int ct = 0; ct < nct; ++ct) {
      int col = w * 128 + ct * 16 + c;
      int blk = col >> 3, cl = col & 7;
#pragma unroll
      for (int rt = 0; rt < 2; ++rt)
#pragma unroll
        for (int r = 0; r < 4; ++r) {
          float p = __expf(s[rt][ct][r] - m_[rt][r]);
          sum[rt][r] += p;
          int row = rt * 16 + g * 4 + r;
          int hsh = (row ^ (row >> 2)) & 7;
          P[row * 512 + ((blk ^ hsh) << 3) + cl] = f2bf(p);
        }
    }
#pragma unroll
    for (int off = 1; off < 16; off <<= 1)
#pragma unroll
      for (int rt = 0; rt < 2; ++rt)
#pragma unroll
        for (int r = 0; r < 4; ++r) sum[rt][r] += __shfl_xor(sum[rt][r], off);
    if (c == 0)
#pragma unroll
      for (int rt = 0; rt < 2; ++rt)
#pragma unroll
        for (int r = 0; r < 4; ++r) ssum[w][rt * 16 + g * 4 + r] = sum[rt][r];
    __syncthreads();

    float li[2][4];
#pragma unroll
    for (int rt = 0; rt < 2; ++rt)
#pragma unroll
      for (int r = 0; r < 4; ++r) {
        int row = rt * 16 + g * 4 + r;
        li[rt][r] = 1.0f / (ssum[0][row] + ssum[1][row] + ssum[2][row] + ssum[3][row]);
      }

    int rt2 = w >> 1, nh = w & 1;
    f32x4 o[2];
    o[0] = (f32x4){0.f, 0.f, 0.f, 0.f};
    o[1] = (f32x4){0.f, 0.f, 0.f, 0.f};
    int nks = bx + 1;
    int prow = rt2 * 16 + c;
    int phsh = (prow ^ (prow >> 2)) & 7;
    for (int ks = 0; ks < nks; ++ks) {
      short8 pa = *(const short8*)&P[prow * 512 + (((ks * 4 + g) ^ phsh) << 3)];
#pragma unroll
      for (int nt = 0; nt < 2; ++nt) {
        int d = nh * 32 + nt * 16 + c;
        short8 vf = *(const short8*)(vb + (size_t)d * 512 + ks * 32 + g * 8);
        o[nt] = MFMA(pa, vf, o[nt]);
      }
    }
#pragma unroll
    for (int nt = 0; nt < 2; ++nt)
#pragma unroll
      for (int r = 0; r < 4; ++r) {
        int trow = q0 + rt2 * 16 + g * 4 + r;
        float val = o[nt][r] * li[rt2][r];
        y[(size_t)(b * 512 + trow) * 1024 + h * 64 + nh * 32 + nt * 16 + c] = f2bf(val);
      }
  }
}

// ---------------- launch ---------------------------------------------------
extern "C" void kernel_launch(void* const* d_in, const int* in_sizes, int n_in,
                              void* d_out, int out_size, void* d_ws, size_t ws_size,
                              hipStream_t stream) {
  const int*   idx   = (const int*)d_in[0];
  const float* xa    = (const float*)d_in[1];
  const float* wte   = (const float*)d_in[2];
  const float* wpe   = (const float*)d_in[3];
  const float* ln1_w = (const float*)d_in[4];
  const float* ln1_b = (const float*)d_in[5];
  const float* sa_wq = (const float*)d_in[6];
  const float* sa_bq = (const float*)d_in[7];
  const float* sa_wk = (const float*)d_in[8];
  const float* sa_bk = (const float*)d_in[9];
  const float* sa_wv = (const float*)d_in[10];
  const float* sa_bv = (const float*)d_in[11];
  const float* sa_wo = (const float*)d_in[12];
  const float* sa_bo = (const float*)d_in[13];
  const float* ca_wq = (const float*)d_in[14];
  const float* ca_bq = (const float*)d_in[15];
  const float* ca_wk = (const float*)d_in[16];
  const float* ca_bk = (const float*)d_in[17];
  const float* ca_wv = (const float*)d_in[18];
  const float* ca_bv = (const float*)d_in[19];
  const float* ca_wo = (const float*)d_in[20];
  const float* ca_bo = (const float*)d_in[21];
  const float* ln2_w = (const float*)d_in[22];
  const float* ln2_b = (const float*)d_in[23];
  const float* fc_w  = (const float*)d_in[24];
  const float* fc_b  = (const float*)d_in[25];
  const float* pr_w  = (const float*)d_in[26];
  const float* pr_b  = (const float*)d_in[27];
  const float* lnf_w = (const float*)d_in[28];
  const float* lnf_b = (const float*)d_in[29];

  const size_t M1 = 1048576;
  float* ws     = (float*)d_ws;
  float* x      = ws;                    // [1024,1024] f32  (4 MB)
  u16* qkvh  = (u16*)(x + M1);           // q,k: [32][512][64]; v: [32][64][512]
  u16* nbf   = qkvh + 3 * M1;            // [1024,1024] bf16
  u16* ybf   = nbf + M1;                 // [1024,1024] bf16
  u16* hmbf  = ybf + M1;                 // [1024,4096] bf16
  u16* xabf  = hmbf + 4 * M1;            // [1024,1024] bf16

  // base (24.75 MB) + optional wtebf (64 MB) + wT (32 MB or 192 MB)
  const bool fullW = ws_size >= 292028416ull;
  const bool full  = fullW || ws_size >= 226492416ull;
  u16* wtebf = xabf + M1;                          // only valid if fullW
  u16* wT    = fullW ? wtebf + (size_t)VV * CC : xabf + M1;
  const size_t wls = full ? 16 * M1 : 0;           // wT layer stride (elems)

  const size_t oQKV = 0, oWO = 3 * M1, oCQ = 4 * M1, oCKV = 5 * M1,
               oCWO = 7 * M1, oFC = 8 * M1, oPR = 12 * M1;

  embed_kernel<<<NTOK, 256, 0, stream>>>(idx, wte, wpe, x);
  convbf_kernel<<<(NTOK * CC / 4 + 255) / 256, 256, 0, stream>>>(xa, xabf, NTOK * CC / 4);
  if (full) {  // all layers' prep (+ wte convert when fullW) in ONE dispatch
    int nz = fullW ? 96 + 32 : 96;
    wtransL_kernel<<<dim3(16, 16, nz), 256, 0, stream>>>(
        sa_wq, sa_wk, sa_wv, sa_wo, ca_wq, ca_wk, ca_wv, ca_wo,
        fc_w, pr_w, wT, wls, 0, 6, wte, wtebf);
  }

  for (int l = 0; l < 6; ++l) {
    size_t bofs = (size_t)l * CC;
    u16* wTl = wT + (size_t)l * wls;

    if (!full)
      wtransL_kernel<<<dim3(16, 16, 16), 256, 0, stream>>>(
          sa_wq, sa_wk, sa_wv, sa_wo, ca_wq, ca_wk, ca_wv, ca_wo,
          fc_w, pr_w, wT, 0, l, 6, nullptr, nullptr);

    // ---- self attention ----
    ln_kernel<<<NTOK, 256, 0, stream>>>(x, ln1_w + bofs, ln1_b + bofs, nbf);
    gemm_bf16_kernel<4, 0, 64, 128, 64, 1><<<dim3(24, 16), 256, 0, stream>>>(
        nbf, nullptr, wTl + oQKV, nullptr, sa_bq + bofs, sa_bk + bofs,
        sa_bv + bofs, (float*)qkvh, CC, 0, 0);
    attn_kernel<<<dim3(8, 32), 256, 0, stream>>>(qkvh, qkvh + M1, qkvh + 2 * M1, ybf);
    gemm_bf16_kernel<1, 0, 32, 64, 64, 2><<<dim3(16, 32, 2), 256, 0, stream>>>(
        ybf, nullptr, wTl + oWO, nullptr, sa_bo + bofs, nullptr, nullptr,
        x, CC, CC, 0);

    // ---- cross attention: cq | ckv merged (independent inputs) ----
    ln_kernel<<<NTOK, 256, 0, stream>>>(x, ln1_w + bofs, ln1_b + bofs, nbf);
    gemm_bf16_kernel<4, 3, 64, 64, 64, 1><<<dim3(48, 16), 256, 0, stream>>>(
        nbf, xabf, wTl + oCQ, wTl + oCKV, ca_bq + bofs, ca_bk + bofs,
        ca_bv + bofs, (float*)qkvh, CC, 0, 0);
    attn_kernel<<<dim3(8, 32), 256, 0, stream>>>(qkvh, qkvh + M1, qkvh + 2 * M1, ybf);
    gemm_bf16_kernel<1, 0, 32, 64, 64, 2><<<dim3(16, 32, 2), 256, 0, stream>>>(
        ybf, nullptr, wTl + oCWO, nullptr, ca_bo + bofs, nullptr, nullptr,
        x, CC, CC, 0);

    // ---- MLP ----
    ln_kernel<<<NTOK, 256, 0, stream>>>(x, ln2_w + bofs, ln2_b + bofs, nbf);
    gemm_bf16_kernel<2, 0, 64, 128, 64, 1><<<dim3(32, 16), 256, 0, stream>>>(
        nbf, nullptr, wTl + oFC, nullptr, fc_b + (size_t)l * DFF_, nullptr,
        nullptr, (float*)hmbf, CC, DFF_, 0);
    gemm_bf16_kernel<1, 0, 32, 64, 64, 4><<<dim3(16, 32, 4), 256, 0, stream>>>(
        hmbf, nullptr, wTl + oPR, nullptr, pr_b + bofs, nullptr, nullptr,
        x, DFF_, CC, 0);
  }

  // ---- final LN + tied lm_head ----
  ln_kernel<<<NTOK, 256, 0, stream>>>(x, lnf_w, lnf_b, nbf);
  if (fullW)   // best-measured round-8 path: bf16 B, BK=64 single-buf
    gemm_bf16_kernel<0, 4, 128, 128, 64, 1><<<dim3(2000), 256, 0, stream>>>(
        nbf, nullptr, wtebf, nullptr, nullptr, nullptr, nullptr,
        (float*)d_out, CC, VV, 0);
  else         // fallback: f32 B reg-staged, BK=32
    gemm_bf16_kernel<0, 2, 128, 128, 32, 1><<<dim3(2000), 256, 0, stream>>>(
        nbf, nullptr, (const u16*)wte, nullptr, nullptr, nullptr, nullptr,
        (float*)d_out, CC, VV, 0);
}

// Round 19
// 1472.548 us; speedup vs baseline: 1.0646x; 1.0099x over previous
//
#include <hip/hip_runtime.h>
#include <math.h>

#define CC   1024
#define HH   16
#define DH   64
#define TT   512
#define NTOK 1024     // B*T
#define DFF_ 4096
#define VV   32000
#define QKSCALE 0.125f   // 1/sqrt(64)

typedef unsigned short u16;
typedef __attribute__((ext_vector_type(8))) short short8;
typedef __attribute__((ext_vector_type(4))) float f32x4;

__device__ __forceinline__ u16 f2bf(float f) {   // RNE fp32->bf16
  union { float f; unsigned u; } v; v.f = f;
  unsigned r = v.u + 0x7FFFu + ((v.u >> 16) & 1u);
  return (u16)(r >> 16);
}
__device__ __forceinline__ float gelu_f(float h) {
  return 0.5f * h * (1.0f + tanhf(0.7978845608028654f * (h + 0.044715f * h * h * h)));
}

// counted vmcnt wait (immediate must be literal in asm string)
template <int N> __device__ __forceinline__ void waitcnt_vm() {
  if constexpr (N == 0) asm volatile("s_waitcnt vmcnt(0)" ::: "memory");
  else if constexpr (N == 1) asm volatile("s_waitcnt vmcnt(1)" ::: "memory");
  else if constexpr (N == 2) asm volatile("s_waitcnt vmcnt(2)" ::: "memory");
  else if constexpr (N == 3) asm volatile("s_waitcnt vmcnt(3)" ::: "memory");
  else if constexpr (N == 4) asm volatile("s_waitcnt vmcnt(4)" ::: "memory");
  else if constexpr (N == 5) asm volatile("s_waitcnt vmcnt(5)" ::: "memory");
  else if constexpr (N == 6) asm volatile("s_waitcnt vmcnt(6)" ::: "memory");
  else if constexpr (N == 7) asm volatile("s_waitcnt vmcnt(7)" ::: "memory");
  else if constexpr (N == 8) asm volatile("s_waitcnt vmcnt(8)" ::: "memory");
  else static_assert(N <= 8, "unsupported vmcnt");
}

// async global->LDS, 16B per lane; dest = wave-uniform base + lane*16
#define GLD16(gp, lp) __builtin_amdgcn_global_load_lds( \
    (const __attribute__((address_space(1))) void*)(gp), \
    (__attribute__((address_space(3))) void*)(lp), 16, 0, 0)

#define MFMA(a, b, c) __builtin_amdgcn_mfma_f32_16x16x32_bf16(a, b, c, 0, 0, 0)

// ---------------- embedding ----------------------------------------------
__global__ __launch_bounds__(256) void embed_kernel(
    const int* __restrict__ idx, const float* __restrict__ wte,
    const float* __restrict__ wpe, float* __restrict__ x) {
  int row = blockIdx.x;
  int t = row & (TT - 1);
  int id = idx[row];
  const float4* a = (const float4*)(wte + (size_t)id * CC);
  const float4* p = (const float4*)(wpe + (size_t)t * CC);
  float4* o = (float4*)(x + (size_t)row * CC);
  int c = threadIdx.x;
  float4 va = a[c], vp = p[c];
  float4 ov;
  ov.x = va.x + vp.x; ov.y = va.y + vp.y; ov.z = va.z + vp.z; ov.w = va.w + vp.w;
  o[c] = ov;
}

// ---------------- layernorm (fp32 in -> bf16 out) ------------------------
__global__ __launch_bounds__(256) void ln_kernel(
    const float* __restrict__ x, const float* __restrict__ w,
    const float* __restrict__ b, u16* __restrict__ out) {
  int row = blockIdx.x, tid = threadIdx.x;
  float4 v = ((const float4*)(x + (size_t)row * CC))[tid];
  float s  = v.x + v.y + v.z + v.w;
  float sq = fmaf(v.x, v.x, fmaf(v.y, v.y, fmaf(v.z, v.z, v.w * v.w)));
  for (int o = 32; o > 0; o >>= 1) { s += __shfl_down(s, o); sq += __shfl_down(sq, o); }
  __shared__ float rs[4], rq[4];
  int wid = tid >> 6, lane = tid & 63;
  if (lane == 0) { rs[wid] = s; rq[wid] = sq; }
  __syncthreads();
  s  = rs[0] + rs[1] + rs[2] + rs[3];
  sq = rq[0] + rq[1] + rq[2] + rq[3];
  float mean = s * (1.0f / CC);
  float var  = sq * (1.0f / CC) - mean * mean;
  float rstd = 1.0f / sqrtf(var + 1e-5f);
  float4 wv = ((const float4*)w)[tid];
  float4 bv = ((const float4*)b)[tid];
  ushort4 o;
  o.x = f2bf((v.x - mean) * rstd * wv.x + bv.x);
  o.y = f2bf((v.y - mean) * rstd * wv.y + bv.y);
  o.z = f2bf((v.z - mean) * rstd * wv.z + bv.z);
  o.w = f2bf((v.w - mean) * rstd * wv.w + bv.w);
  ((ushort4*)(out + (size_t)row * CC))[tid] = o;
}

// ---------------- weight prep: 16 transposes per layer, z = l*16 + slot --
// slot 0-7: squares; 8-11: fc col-slices; 12-15: pr row-slices.
__global__ __launch_bounds__(256) void wtransL_kernel(
    const float* __restrict__ w0, const float* __restrict__ w1,
    const float* __restrict__ w2, const float* __restrict__ w3,
    const float* __restrict__ w4, const float* __restrict__ w5,
    const float* __restrict__ w6, const float* __restrict__ w7,
    const float* __restrict__ fc, const float* __restrict__ pr,
    u16* __restrict__ wt, size_t dls, int lbase) {
  const size_t M1 = 1048576;
  int z = blockIdx.z;
  int l = lbase + (z >> 4), slot = z & 15;
  size_t wofs = (size_t)l * M1;          // square weights: l*C*C
  size_t mofs = (size_t)l * 4 * M1;      // fc/pr: l*C*DFF
  const float* src;
  size_t doff = (size_t)(l - lbase) * dls;
  int sstr, dstr;
  if (slot < 8) {
    const float* base = slot == 0 ? w0 : slot == 1 ? w1 : slot == 2 ? w2
                      : slot == 3 ? w3 : slot == 4 ? w4 : slot == 5 ? w5
                      : slot == 6 ? w6 : w7;
    src = base + wofs; sstr = 1024; doff += (size_t)slot * M1; dstr = 1024;
  } else if (slot < 12) {
    int s = slot - 8;
    src = fc + mofs + (size_t)s * 1024; sstr = 4096;
    doff += 8 * M1 + (size_t)s * M1; dstr = 1024;
  } else {
    int s = slot - 12;
    src = pr + mofs + (size_t)s * M1; sstr = 1024;
    doff += 12 * M1 + (size_t)s * 1024; dstr = 4096;
  }
  __shared__ float t[64][65];
  int bx = blockIdx.x * 64, by = blockIdx.y * 64;
  int tid = threadIdx.x;
  int r16 = tid >> 4;          // 0..15
  int c4  = (tid & 15) * 4;    // 0..60
#pragma unroll
  for (int i = 0; i < 4; ++i) {
    int row = r16 + i * 16;
    float4 v = *(const float4*)&src[(size_t)(by + row) * sstr + bx + c4];
    t[row][c4] = v.x; t[row][c4 + 1] = v.y; t[row][c4 + 2] = v.z; t[row][c4 + 3] = v.w;
  }
  __syncthreads();
#pragma unroll
  for (int i = 0; i < 4; ++i) {
    int orow = r16 + i * 16;   // output row n = bx+orow; k = by+c4..+3
    ushort4 o;
    o.x = f2bf(t[c4 + 0][orow]);
    o.y = f2bf(t[c4 + 1][orow]);
    o.z = f2bf(t[c4 + 2][orow]);
    o.w = f2bf(t[c4 + 3][orow]);
    *(ushort4*)&wt[doff + (size_t)(bx + orow) * dstr + by + c4] = o;
  }
}

// ---------------- elementwise f32 -> bf16, 32B read / 16B write ----------
__global__ __launch_bounds__(256) void convbf8_kernel(
    const float* __restrict__ in, u16* __restrict__ out, int n8) {
  int i = blockIdx.x * 256 + threadIdx.x;
  if (i < n8) {
    float4 a = ((const float4*)in)[2 * i];
    float4 b = ((const float4*)in)[2 * i + 1];
    u16 t[8] = {f2bf(a.x), f2bf(a.y), f2bf(a.z), f2bf(a.w),
                f2bf(b.x), f2bf(b.y), f2bf(b.z), f2bf(b.w)};
    *(short8*)&out[(size_t)i * 8] = *(short8*)t;
  }
}

// ---------------- bf16 MFMA GEMM, XOR-swizzled LDS -----------------------
// C[M,N](ldc) = epi(A[M,K] @ B^T + bias);  A[M,K], B[N,K] bf16 row-major.
// MODE 0/3: triple-buffered counted-vmcnt pipeline (2 stages in flight).
// MODE 2: lm_head fallback (XCD swizzle + B reg-staged from f32, BK=32).
// MODE 4: lm_head best-measured: XCD swizzle + bf16 B via GLD16,
//         single-buffered stage/sync/compute/sync loop, 32KB LDS.
// EPI: 0=store f32(+bias), 1=f32 += residual (atomic when SK>1),
//      2=bf16 gelu(+bias), 4=bf16 per-head scatter
// SK: split-K factor (blockIdx.z selects split; bias applied by split 0)
template <int EPI, int MODE, int BM, int BN, int BK, int SK>
__global__ __launch_bounds__(256) void gemm_bf16_kernel(
    const u16* __restrict__ A, const u16* __restrict__ A2,
    const u16* __restrict__ B, const u16* __restrict__ B2,
    const float* __restrict__ bias, const float* __restrict__ bias2,
    const float* __restrict__ bias3, float* __restrict__ Cm,
    int K, int ldc, int whichbase) {
  constexpr int WM = BM / 2, WN = BN / 2, MF = WM / 16, NF = WN / 16;
  constexpr int KS = BK / 32;
  constexpr int NB = BK / 8;
  constexpr int PA = BM * BK / 2048;
  constexpr int PB = BN * BK / 2048;
  constexpr int RPP = 2048 / BK;
  constexpr int NBUF = (MODE == 2) ? 2 : (MODE == 4 ? 1 : 3);
  __shared__ u16 As[NBUF][BM * BK];
  __shared__ u16 Bs[NBUF][BN * BK];
  int tid = threadIdx.x;
  int lane = tid & 63, wave = tid >> 6;
  int wr = wave >> 1, wc = wave & 1;
  int row0, col0;
  bool isq = true;
  const u16* Ause = A;
  const u16* Buse = B;
  if (MODE == 2 || MODE == 4) {
    int id = blockIdx.x;                 // 0..1999
    int wg = (id & 7) * 250 + (id >> 3); // bijective XCD swizzle
    row0 = (wg & 7) * BM;
    col0 = (wg >> 3) * BN;
  } else if (MODE == 3) {
    int bx = blockIdx.x;
    isq = bx < (1024 / BN);
    Ause = isq ? A : A2;
    Buse = isq ? B : B2;
    col0 = (isq ? bx : bx - 1024 / BN) * BN;
    row0 = blockIdx.y * BM;
  } else {
    row0 = blockIdx.y * BM;
    col0 = blockIdx.x * BN;
  }
  const int split = (SK > 1) ? blockIdx.z : 0;
  const int Kloc = K / SK;
  const int kbase = split * Kloc;
  f32x4 acc[MF][NF];
#pragma unroll
  for (int m = 0; m < MF; ++m)
#pragma unroll
    for (int n = 0; n < NF; ++n) acc[m][n] = (f32x4){0.f, 0.f, 0.f, 0.f};

  int srow = tid / NB;
  int sblk = (BK == 64) ? ((tid & 7) ^ ((tid >> 3) & 7))
                        : ((tid & 3) ^ ((tid >> 3) & 3));
  const u16* Ab = Ause + (size_t)row0 * K + kbase;
  int arow = wr * WM + (lane & 15);
  int brow = wc * WN + (lane & 15);
  int g8 = lane >> 4;
  const int NT = Kloc / BK;

  auto compute = [&](const u16* Ac, const u16* Bc) {
#pragma unroll
    for (int ks = 0; ks < KS; ++ks) {
      short8 af[MF], bg[NF];
#pragma unroll
      for (int m = 0; m < MF; ++m) {
        int row = arow + m * 16;
        int off = (BK == 64) ? row * 64 + (((ks * 4 + g8) ^ (row & 7)) << 3)
                             : row * 32 + ((g8 ^ ((row >> 1) & 3)) << 3);
        af[m] = *(const short8*)&Ac[off];
      }
#pragma unroll
      for (int n = 0; n < NF; ++n) {
        int row = brow + n * 16;
        int off = (BK == 64) ? row * 64 + (((ks * 4 + g8) ^ (row & 7)) << 3)
                             : row * 32 + ((g8 ^ ((row >> 1) & 3)) << 3);
        bg[n] = *(const short8*)&Bc[off];
      }
      __builtin_amdgcn_s_setprio(1);
#pragma unroll
      for (int m = 0; m < MF; ++m)
#pragma unroll
        for (int n = 0; n < NF; ++n)
          acc[m][n] = MFMA(af[m], bg[n], acc[m][n]);
      __builtin_amdgcn_s_setprio(0);
    }
  };

  if constexpr (MODE == 2) {
    // B reg-staged from f32 (wte is [N][K] f32), BK=32 fallback
    const float* Bf = (const float*)B;
    int bsr = tid >> 2;                  // 0..63 (row within 64-row pass)
    int bkb = tid & 3;                   // 8-k block
    float4 rb0, rb1, rb2, rb3;
    auto loadB = [&](int k0) {
      const float* p0 = Bf + (size_t)(col0 + bsr) * 1024 + k0 + bkb * 8;
      const float* p1 = Bf + (size_t)(col0 + 64 + bsr) * 1024 + k0 + bkb * 8;
      rb0 = *(const float4*)p0; rb1 = *(const float4*)(p0 + 4);
      rb2 = *(const float4*)p1; rb3 = *(const float4*)(p1 + 4);
    };
    auto writeB = [&](int bufi) {
      u16 t0[8] = {f2bf(rb0.x), f2bf(rb0.y), f2bf(rb0.z), f2bf(rb0.w),
                   f2bf(rb1.x), f2bf(rb1.y), f2bf(rb1.z), f2bf(rb1.w)};
      u16 t1[8] = {f2bf(rb2.x), f2bf(rb2.y), f2bf(rb2.z), f2bf(rb2.w),
                   f2bf(rb3.x), f2bf(rb3.y), f2bf(rb3.z), f2bf(rb3.w)};
      int r1 = 64 + bsr;
      *(short8*)&Bs[bufi][bsr * 32 + ((bkb ^ ((bsr >> 1) & 3)) << 3)] = *(short8*)t0;
      *(short8*)&Bs[bufi][r1 * 32 + ((bkb ^ ((r1 >> 1) & 3)) << 3)] = *(short8*)t1;
    };
    auto stageA = [&](int bufi, int k0) {
#pragma unroll
      for (int p = 0; p < PA; ++p)
        GLD16(Ab + (size_t)(p * RPP + srow) * K + k0 + sblk * 8,
              &As[bufi][p * 2048 + wave * 512]);
    };
    loadB(0);
    stageA(0, 0);
    writeB(0);
    __syncthreads();
    for (int t = 0; t < NT; ++t) {
      int cur = t & 1;
      if (t + 1 < NT) { loadB((t + 1) * BK); stageA(cur ^ 1, (t + 1) * BK); }
      compute(As[cur], Bs[cur]);
      if (t + 1 < NT) writeB(cur ^ 1);   // cvt+ds_write after MFMAs (T14)
      __syncthreads();
    }
  } else if constexpr (MODE == 4) {
    // round-8 structure: single-buffered, GLD16 both operands (bf16 B)
    const u16* Bb = Buse + (size_t)col0 * K + kbase;
    for (int t = 0; t < NT; ++t) {
      int k0 = t * BK;
#pragma unroll
      for (int p = 0; p < PA; ++p)
        GLD16(Ab + (size_t)(p * RPP + srow) * K + k0 + sblk * 8,
              &As[0][p * 2048 + wave * 512]);
#pragma unroll
      for (int p = 0; p < PB; ++p)
        GLD16(Bb + (size_t)(p * RPP + srow) * K + k0 + sblk * 8,
              &Bs[0][p * 2048 + wave * 512]);
      __syncthreads();            // compiler drains vmcnt here
      compute(As[0], Bs[0]);
      __syncthreads();
    }
  } else {
    const u16* Bb = Buse + (size_t)col0 * K + kbase;
    auto stage = [&](int bufi, int k0) {
#pragma unroll
      for (int p = 0; p < PA; ++p)
        GLD16(Ab + (size_t)(p * RPP + srow) * K + k0 + sblk * 8,
              &As[bufi][p * 2048 + wave * 512]);
#pragma unroll
      for (int p = 0; p < PB; ++p)
        GLD16(Bb + (size_t)(p * RPP + srow) * K + k0 + sblk * 8,
              &Bs[bufi][p * 2048 + wave * 512]);
    };
    // T4 pipeline: 2 stages in flight, counted vmcnt, raw barriers.
    stage(0, 0);
    if (NT > 1) stage(1, BK);
    for (int t = 0; t < NT; ++t) {
      if (t + 1 < NT) waitcnt_vm<PA + PB>();  // tile t resident; t+1 in flight
      else            waitcnt_vm<0>();        // final drain
      __builtin_amdgcn_s_barrier();
      __builtin_amdgcn_sched_barrier(0);
      if (t + 2 < NT) stage((t + 2) % 3, (t + 2) * BK);
      int cur = t % 3;
      compute(As[cur], Bs[cur]);
      // no trailing barrier: 3 buffers + next-iter barrier protect reuse
    }
  }

  int r0 = row0 + wr * WM + g8 * 4;
  int c0 = col0 + wc * WN + (lane & 15);

  if (EPI == 4) {
    // scatter to per-head layouts: q/k [bh][t][d], v [bh][d][t]
    u16* qb = (u16*)Cm;
#pragma unroll
    for (int m = 0; m < MF; ++m)
#pragma unroll
      for (int n = 0; n < NF; ++n) {
        int j = c0 + n * 16;
        int which = (MODE == 3 ? (isq ? 0 : 1) : whichbase) + (j >> 10);
        const float* bp = which == 0 ? bias : (which == 1 ? bias2 : bias3);
        float bj = bp ? bp[j & 1023] : 0.0f;
        int h = (j & 1023) >> 6, d = j & 63;
        int trow0 = r0 + m * 16;
        int b = trow0 >> 9, t0 = trow0 & 511;
        int bh = b * 16 + h;
        u16 vals[4];
#pragma unroll
        for (int r = 0; r < 4; ++r) vals[r] = f2bf(acc[m][n][r] + bj);
        if (which < 2) {
          u16* dst = qb + (size_t)which * 1048576 + (size_t)bh * 32768 + (size_t)t0 * 64 + d;
#pragma unroll
          for (int r = 0; r < 4; ++r) dst[(size_t)r * 64] = vals[r];
        } else {
          u16* dst = qb + 2 * 1048576 + (size_t)bh * 32768 + (size_t)d * 512 + t0;
          *(ushort4*)dst = *(ushort4*)vals;
        }
      }
    return;
  }

  float bj[NF];
#pragma unroll
  for (int n = 0; n < NF; ++n)
    bj[n] = bias ? bias[c0 + n * 16] : 0.0f;
  u16* Cb = (u16*)Cm;
#pragma unroll
  for (int m = 0; m < MF; ++m)
#pragma unroll
    for (int n = 0; n < NF; ++n)
#pragma unroll
      for (int r = 0; r < 4; ++r) {
        size_t off = (size_t)(r0 + m * 16 + r) * ldc + c0 + n * 16;
        float v = acc[m][n][r] + ((SK == 1 || split == 0) ? bj[n] : 0.0f);
        if (EPI == 0) Cm[off] = v;
        else if (EPI == 1) {
          if constexpr (SK > 1) atomicAdd(&Cm[off], v);
          else Cm[off] += v;
        }
        else if (EPI == 2) Cb[off] = f2bf(gelu_f(v));
      }
}

// ---------------- fused flash attention (causal, incl. cross per ref) ----
// q,k: [32 bh][512 t][64 d] bf16;  v: [32 bh][64 d][512 t] bf16
// y: [1024 tok][1024 C] bf16.  Grid (8 paired q-tiles, 32 bh), 256 threads.
// Causal balance: block handles q-tiles {bx, 15-bx} (work i+1 -> 17/pair).
__global__ __launch_bounds__(256) void attn_kernel(
    const u16* __restrict__ qh, const u16* __restrict__ kh,
    const u16* __restrict__ vt, u16* __restrict__ y) {
  __shared__ u16 P[32 * 512];             // swizzled probs
  __shared__ float smax[4][32], ssum[4][32];
  int tid = threadIdx.x, lane = tid & 63, w = tid >> 6;
  int bh = blockIdx.y;
  int b = bh >> 4, h = bh & 15;
  const u16* qb = qh + (size_t)bh * 32768;
  const u16* kb = kh + (size_t)bh * 32768;
  const u16* vb = vt + (size_t)bh * 32768;
  int g = lane >> 4, c = lane & 15;

  for (int half = 0; half < 2; ++half) {
    int bx = half == 0 ? (int)blockIdx.x : 15 - (int)blockIdx.x;
    if (half) __syncthreads();            // protect P/smax/ssum reuse
    int q0 = bx * 32;

    short8 a[2][2];
#pragma unroll
    for (int rt = 0; rt < 2; ++rt)
#pragma unroll
      for (int ks = 0; ks < 2; ++ks)
        a[rt][ks] = *(const short8*)(qb + (size_t)(q0 + rt * 16 + c) * 64 + ks * 32 + g * 8);

    int lim = q0 + 31;
    int nct = (lim - w * 128) / 16 + 1;
    if (nct > 8) nct = 8;
    if (nct < 0) nct = 0;
    f32x4 s[2][8];
#pragma unroll
    for (int rt = 0; rt < 2; ++rt)
#pragma unroll
      for (int ct = 0; ct < 8; ++ct) s[rt][ct] = (f32x4){0.f, 0.f, 0.f, 0.f};
    for (int ct = 0; ct < nct; ++ct) {
      int n0 = w * 128 + ct * 16;
#pragma unroll
      for (int ks = 0; ks < 2; ++ks) {
        short8 bf = *(const short8*)(kb + (size_t)(n0 + c) * 64 + ks * 32 + g * 8);
        s[0][ct] = MFMA(a[0][ks], bf, s[0][ct]);
        s[1][ct] = MFMA(a[1][ks], bf, s[1][ct]);
      }
    }

    float mx[2][4];
#pragma unroll
    for (int rt = 0; rt < 2; ++rt)
#pragma unroll
      for (int r = 0; r < 4; ++r) mx[rt][r] = -1e30f;
    for (int ct = 0; ct < nct; ++ct) {
      int col = w * 128 + ct * 16 + c;
#pragma unroll
      for (int rt = 0; rt < 2; ++rt)
#pragma unroll
        for (int r = 0; r < 4; ++r) {
          int trow = q0 + rt * 16 + g * 4 + r;
          float v = s[rt][ct][r] * QKSCALE;
          if (col > trow) v = -1e30f;
          s[rt][ct][r] = v;
          mx[rt][r] = fmaxf(mx[rt][r], v);
        }
    }
#pragma unroll
    for (int off = 1; off < 16; off <<= 1)
#pragma unroll
      for (int rt = 0; rt < 2; ++rt)
#pragma unroll
        for (int r = 0; r < 4; ++r) mx[rt][r] = fmaxf(mx[rt][r], __shfl_xor(mx[rt][r], off));
    if (c == 0)
#pragma unroll
      for (int rt = 0; rt < 2; ++rt)
#pragma unroll
        for (int r = 0; r < 4; ++r) smax[w][rt * 16 + g * 4 + r] = mx[rt][r];
    __syncthreads();

    float m_[2][4], sum[2][4];
#pragma unroll
    for (int rt = 0; rt < 2; ++rt)
#pragma unroll
      for (int r = 0; r < 4; ++r) {
        int row = rt * 16 + g * 4 + r;
        m_[rt][r] = fmaxf(fmaxf(smax[0][row], smax[1][row]), fmaxf(smax[2][row], smax[3][row]));
        sum[rt][r] = 0.f;
      }
    for (int ct = 0; ct < nct; ++ct) {
      int col = w * 128 + ct * 16 + c;
      int blk = col >> 3, cl = col & 7;
#pragma unroll
      for (int rt = 0; rt < 2; ++rt)
#pragma unroll
        for (int r = 0; r < 4; ++r) {
          float p = __expf(s[rt][ct][r] - m_[rt][r]);
          sum[rt][r] += p;
          int row = rt * 16 + g * 4 + r;
          int hsh = (row ^ (row >> 2)) & 7;
          P[row * 512 + ((blk ^ hsh) << 3) + cl] = f2bf(p);
        }
    }
#pragma unroll
    for (int off = 1; off < 16; off <<= 1)
#pragma unroll
      for (int rt = 0; rt < 2; ++rt)
#pragma unroll
        for (int r = 0; r < 4; ++r) sum[rt][r] += __shfl_xor(sum[rt][r], off);
    if (c == 0)
#pragma unroll
      for (int rt = 0; rt < 2; ++rt)
#pragma unroll
        for (int r = 0; r < 4; ++r) ssum[w][rt * 16 + g * 4 + r] = sum[rt][r];
    __syncthreads();

    float li[2][4];
#pragma unroll
    for (int rt = 0; rt < 2; ++rt)
#pragma unroll
      for (int r = 0; r < 4; ++r) {
        int row = rt * 16 + g * 4 + r;
        li[rt][r] = 1.0f / (ssum[0][row] + ssum[1][row] + ssum[2][row] + ssum[3][row]);
      }

    int rt2 = w >> 1, nh = w & 1;
    f32x4 o[2];
    o[0] = (f32x4){0.f, 0.f, 0.f, 0.f};
    o[1] = (f32x4){0.f, 0.f, 0.f, 0.f};
    int nks = bx + 1;
    int prow = rt2 * 16 + c;
    int phsh = (prow ^ (prow >> 2)) & 7;
    for (int ks = 0; ks < nks; ++ks) {
      short8 pa = *(const short8*)&P[prow * 512 + (((ks * 4 + g) ^ phsh) << 3)];
#pragma unroll
      for (int nt = 0; nt < 2; ++nt) {
        int d = nh * 32 + nt * 16 + c;
        short8 vf = *(const short8*)(vb + (size_t)d * 512 + ks * 32 + g * 8);
        o[nt] = MFMA(pa, vf, o[nt]);
      }
    }
#pragma unroll
    for (int nt = 0; nt < 2; ++nt)
#pragma unroll
      for (int r = 0; r < 4; ++r) {
        int trow = q0 + rt2 * 16 + g * 4 + r;
        float val = o[nt][r] * li[rt2][r];
        y[(size_t)(b * 512 + trow) * 1024 + h * 64 + nh * 32 + nt * 16 + c] = f2bf(val);
      }
  }
}

// ---------------- launch ---------------------------------------------------
extern "C" void kernel_launch(void* const* d_in, const int* in_sizes, int n_in,
                              void* d_out, int out_size, void* d_ws, size_t ws_size,
                              hipStream_t stream) {
  const int*   idx   = (const int*)d_in[0];
  const float* xa    = (const float*)d_in[1];
  const float* wte   = (const float*)d_in[2];
  const float* wpe   = (const float*)d_in[3];
  const float* ln1_w = (const float*)d_in[4];
  const float* ln1_b = (const float*)d_in[5];
  const float* sa_wq = (const float*)d_in[6];
  const float* sa_bq = (const float*)d_in[7];
  const float* sa_wk = (const float*)d_in[8];
  const float* sa_bk = (const float*)d_in[9];
  const float* sa_wv = (const float*)d_in[10];
  const float* sa_bv = (const float*)d_in[11];
  const float* sa_wo = (const float*)d_in[12];
  const float* sa_bo = (const float*)d_in[13];
  const float* ca_wq = (const float*)d_in[14];
  const float* ca_bq = (const float*)d_in[15];
  const float* ca_wk = (const float*)d_in[16];
  const float* ca_bk = (const float*)d_in[17];
  const float* ca_wv = (const float*)d_in[18];
  const float* ca_bv = (const float*)d_in[19];
  const float* ca_wo = (const float*)d_in[20];
  const float* ca_bo = (const float*)d_in[21];
  const float* ln2_w = (const float*)d_in[22];
  const float* ln2_b = (const float*)d_in[23];
  const float* fc_w  = (const float*)d_in[24];
  const float* fc_b  = (const float*)d_in[25];
  const float* pr_w  = (const float*)d_in[26];
  const float* pr_b  = (const float*)d_in[27];
  const float* lnf_w = (const float*)d_in[28];
  const float* lnf_b = (const float*)d_in[29];

  const size_t M1 = 1048576;
  float* ws     = (float*)d_ws;
  float* x      = ws;                    // [1024,1024] f32  (4 MB)
  u16* qkvh  = (u16*)(x + M1);           // q,k: [32][512][64]; v: [32][64][512]
  u16* nbf   = qkvh + 3 * M1;            // [1024,1024] bf16
  u16* ybf   = nbf + M1;                 // [1024,1024] bf16
  u16* hmbf  = ybf + M1;                 // [1024,4096] bf16
  u16* xabf  = hmbf + 4 * M1;            // [1024,1024] bf16

  // base (24.75 MB) + optional wtebf (64 MB) + wT (32 MB or 192 MB)
  const bool fullW = ws_size >= 292028416ull;
  const bool full  = fullW || ws_size >= 226492416ull;
  u16* wtebf = xabf + M1;                          // only valid if fullW
  u16* wT    = fullW ? wtebf + (size_t)VV * CC : xabf + M1;
  const size_t wls = full ? 16 * M1 : 0;           // wT layer stride (elems)

  const size_t oQKV = 0, oWO = 3 * M1, oCQ = 4 * M1, oCKV = 5 * M1,
               oCWO = 7 * M1, oFC = 8 * M1, oPR = 12 * M1;

  embed_kernel<<<NTOK, 256, 0, stream>>>(idx, wte, wpe, x);
  convbf8_kernel<<<(NTOK * CC / 8 + 255) / 256, 256, 0, stream>>>(
      xa, xabf, NTOK * CC / 8);
  if (fullW)   // wte f32->bf16, 16B/lane stores
    convbf8_kernel<<<(VV * CC / 8 + 255) / 256, 256, 0, stream>>>(
        wte, wtebf, VV * CC / 8);
  if (full)    // all 6 layers' transposes in ONE dispatch
    wtransL_kernel<<<dim3(16, 16, 96), 256, 0, stream>>>(
        sa_wq, sa_wk, sa_wv, sa_wo, ca_wq, ca_wk, ca_wv, ca_wo,
        fc_w, pr_w, wT, wls, 0);

  for (int l = 0; l < 6; ++l) {
    size_t bofs = (size_t)l * CC;
    u16* wTl = wT + (size_t)l * wls;

    if (!full)
      wtransL_kernel<<<dim3(16, 16, 16), 256, 0, stream>>>(
          sa_wq, sa_wk, sa_wv, sa_wo, ca_wq, ca_wk, ca_wv, ca_wo,
          fc_w, pr_w, wT, 0, l);

    // ---- self attention ----
    ln_kernel<<<NTOK, 256, 0, stream>>>(x, ln1_w + bofs, ln1_b + bofs, nbf);
    gemm_bf16_kernel<4, 0, 64, 128, 64, 1><<<dim3(24, 16), 256, 0, stream>>>(
        nbf, nullptr, wTl + oQKV, nullptr, sa_bq + bofs, sa_bk + bofs,
        sa_bv + bofs, (float*)qkvh, CC, 0, 0);
    attn_kernel<<<dim3(8, 32), 256, 0, stream>>>(qkvh, qkvh + M1, qkvh + 2 * M1, ybf);
    gemm_bf16_kernel<1, 0, 32, 64, 64, 2><<<dim3(16, 32, 2), 256, 0, stream>>>(
        ybf, nullptr, wTl + oWO, nullptr, sa_bo + bofs, nullptr, nullptr,
        x, CC, CC, 0);

    // ---- cross attention: cq | ckv merged (independent inputs) ----
    ln_kernel<<<NTOK, 256, 0, stream>>>(x, ln1_w + bofs, ln1_b + bofs, nbf);
    gemm_bf16_kernel<4, 3, 64, 64, 64, 1><<<dim3(48, 16), 256, 0, stream>>>(
        nbf, xabf, wTl + oCQ, wTl + oCKV, ca_bq + bofs, ca_bk + bofs,
        ca_bv + bofs, (float*)qkvh, CC, 0, 0);
    attn_kernel<<<dim3(8, 32), 256, 0, stream>>>(qkvh, qkvh + M1, qkvh + 2 * M1, ybf);
    gemm_bf16_kernel<1, 0, 32, 64, 64, 2><<<dim3(16, 32, 2), 256, 0, stream>>>(
        ybf, nullptr, wTl + oCWO, nullptr, ca_bo + bofs, nullptr, nullptr,
        x, CC, CC, 0);

    // ---- MLP ----
    ln_kernel<<<NTOK, 256, 0, stream>>>(x, ln2_w + bofs, ln2_b + bofs, nbf);
    gemm_bf16_kernel<2, 0, 64, 128, 64, 1><<<dim3(32, 16), 256, 0, stream>>>(
        nbf, nullptr, wTl + oFC, nullptr, fc_b + (size_t)l * DFF_, nullptr,
        nullptr, (float*)hmbf, CC, DFF_, 0);
    gemm_bf16_kernel<1, 0, 32, 64, 64, 4><<<dim3(16, 32, 4), 256, 0, stream>>>(
        hmbf, nullptr, wTl + oPR, nullptr, pr_b + bofs, nullptr, nullptr,
        x, DFF_, CC, 0);
  }

  // ---- final LN + tied lm_head ----
  ln_kernel<<<NTOK, 256, 0, stream>>>(x, lnf_w, lnf_b, nbf);
  if (fullW)   // best-measured round-8 path: bf16 B, BK=64 single-buf
    gemm_bf16_kernel<0, 4, 128, 128, 64, 1><<<dim3(2000), 256, 0, stream>>>(
        nbf, nullptr, wtebf, nullptr, nullptr, nullptr, nullptr,
        (float*)d_out, CC, VV, 0);
  else         // fallback: f32 B reg-staged, BK=32
    gemm_bf16_kernel<0, 2, 128, 128, 32, 1><<<dim3(2000), 256, 0, stream>>>(
        nbf, nullptr, (const u16*)wte, nullptr, nullptr, nullptr, nullptr,
        (float*)d_out, CC, VV, 0);
}